// Round 5
// baseline (311.987 us; speedup 1.0000x reference)
//
#include <hip/hip_runtime.h>
#include <hip/hip_cooperative_groups.h>
#include <math.h>

namespace cg = cooperative_groups;

// Problem constants
#define B     64
#define S1    513
#define S     512
#define H     768
#define T     4
#define START 2
#define STOP  3

// d_out layout (floats), reference tuple order:
// (isqa_pred[64,1], crf_pred[64,512], isqa_loss, crf_loss, tags[64,512], IsQA[64,1])
#define OUT_ISQA_PRED 0
#define OUT_CRF_PRED  64
#define OUT_ISQA_LOSS 32832
#define OUT_CRF_LOSS  32833
#define OUT_TAGS      32834
#define OUT_ISQA      65602

// ws layout (floats)
#define WS_FEATS  0                  // [B][S][T]  normal layout
#define WS_LOGITS (B*S*T)            // 131072: [B][2]
#define WS_ZG     (B*S*T + 2*B)      // 131200: [B]
#define WS_CNT    (B*S*T + 3*B)      // 131264: int counter
#define WS_FEATST 131280             // [B][T][S] transposed layout

// ---------------------------------------------------------------------------
// DPP helpers (quad_perm broadcasts/butterflies within groups of 4 lanes)
// ---------------------------------------------------------------------------
template<int CTRL>
__device__ __forceinline__ float dppf(float x) {
    int v = __builtin_amdgcn_update_dpp(__builtin_bit_cast(int, x),
                                        __builtin_bit_cast(int, x),
                                        CTRL, 0xF, 0xF, false);
    return __builtin_bit_cast(float, v);
}
template<int CTRL>
__device__ __forceinline__ int dppi(int x) {
    return __builtin_amdgcn_update_dpp(x, x, CTRL, 0xF, 0xF, false);
}

__device__ __forceinline__ float lse4(float x0, float x1, float x2, float x3) {
    float m = fmaxf(fmaxf(x0, x1), fmaxf(x2, x3));
    return m + __logf(__expf(x0 - m) + __expf(x1 - m) +
                      __expf(x2 - m) + __expf(x3 - m));
}

// full-wave sum reduction: DPP xor1/xor2 + shfl xor4..32 (result in all lanes)
__device__ __forceinline__ float wred(float a) {
    a += dppf<0xB1>(a); a += dppf<0x4E>(a);
    a += __shfl_xor(a, 4); a += __shfl_xor(a, 8);
    a += __shfl_xor(a, 16); a += __shfl_xor(a, 32);
    return a;
}

__device__ __forceinline__ float dot4(float4 e, float4 w) {
    return e.x * w.x + e.y * w.y + e.z * w.z + e.w * w.w;
}

// ---------------------------------------------------------------------------
// Viterbi step: bit-exact value path (max of exact sums + add), first-index
// argmax; returns quad-packed map word (byte j = argmax for state j).
// ---------------------------------------------------------------------------
__device__ __forceinline__ unsigned int vstep(
    float& d, float fv,
    float tc0, float tc1, float tc2, float tc3, int sh8j)
{
    const float d0 = dppf<0x00>(d), d1 = dppf<0x55>(d);
    const float d2 = dppf<0xAA>(d), d3 = dppf<0xFF>(d);
    const float y0 = d0 + tc0, y1 = d1 + tc1;
    const float y2 = d2 + tc2, y3 = d3 + tc3;
    const float m01 = fmaxf(y0, y1), m23 = fmaxf(y2, y3);
    const int   i01 = (y1 > y0) ? 1 : 0;
    const int   i23 = (y3 > y2) ? 3 : 2;
    const int   bi  = (m23 > m01) ? i23 : i01;
    d = fmaxf(m01, m23) + fv;
    unsigned int mb = (unsigned int)bi << sh8j;      // byte slot j
    unsigned int t1 = mb | (unsigned int)dppi<0xB1>((int)mb);
    return t1 | (unsigned int)dppi<0x4E>((int)t1);
}

// ---------------------------------------------------------------------------
// Fused cooperative kernel, grid 512 x 256.
// Phase 1 (all blocks): feats GEMV (normal + transposed layouts).
// grid.sync()
// Phase 2: blocks 0..63 = Z / gold / tags / losses; 64..79 = Viterbi; rest exit.
// ---------------------------------------------------------------------------
__global__ __launch_bounds__(256) void fused_kernel(
    const int* __restrict__ ans, const int* __restrict__ isqa,
    const float* __restrict__ emb,
    const float* __restrict__ fc2_W, const float* __restrict__ fc2_b,
    const float* __restrict__ crf_W, const float* __restrict__ crf_b,
    const float* __restrict__ trans,
    float* __restrict__ ws, float* __restrict__ out)
{
    __shared__ float smemf[8208];    // V: sfT 8192 + 16 pad; Z: 3076 used
    __shared__ int isLast;
    const int tid  = threadIdx.x;
    const int lane = tid & 63;
    const int blk  = blockIdx.x;

    // ===================== Phase 1: feats =====================
    if (blk == 0 && tid == 0) ((int*)ws)[WS_CNT] = 0;
    {
        const int wid = blk * 4 + (tid >> 6);        // 0..2047
        const float4* __restrict__ W4 = (const float4*)crf_W;  // [4][192]
        float4 wr[4][3];
        #pragma unroll
        for (int o = 0; o < 4; ++o)
            #pragma unroll
            for (int k = 0; k < 3; ++k)
                wr[o][k] = W4[o * 192 + lane + 64 * k];
        const float cb0 = crf_b[0], cb1 = crf_b[1], cb2 = crf_b[2], cb3 = crf_b[3];
        float* __restrict__ fN = ws + WS_FEATS;
        float* __restrict__ fT = ws + WS_FEATST;

        #pragma unroll 2
        for (int i = 0; i < 16; i += 2) {
            const int r0 = wid + 2048 * i;
            const int r1 = wid + 2048 * (i + 1);
            const int b0 = r0 >> 9, s0 = (r0 & 511) + 1;
            const int b1 = r1 >> 9, s1 = (r1 & 511) + 1;
            const float4* __restrict__ p0 =
                (const float4*)emb + (size_t)(b0 * S1 + s0) * (H / 4);
            const float4* __restrict__ p1 =
                (const float4*)emb + (size_t)(b1 * S1 + s1) * (H / 4);
            float4 e0[3], e1[3];
            #pragma unroll
            for (int k = 0; k < 3; ++k) e0[k] = p0[lane + 64 * k];
            #pragma unroll
            for (int k = 0; k < 3; ++k) e1[k] = p1[lane + 64 * k];

            float a00 = 0.f, a01 = 0.f, a02 = 0.f, a03 = 0.f;
            float a10 = 0.f, a11 = 0.f, a12 = 0.f, a13 = 0.f;
            #pragma unroll
            for (int k = 0; k < 3; ++k) {
                a00 += dot4(e0[k], wr[0][k]); a01 += dot4(e0[k], wr[1][k]);
                a02 += dot4(e0[k], wr[2][k]); a03 += dot4(e0[k], wr[3][k]);
                a10 += dot4(e1[k], wr[0][k]); a11 += dot4(e1[k], wr[1][k]);
                a12 += dot4(e1[k], wr[2][k]); a13 += dot4(e1[k], wr[3][k]);
            }
            a00 = wred(a00); a01 = wred(a01); a02 = wred(a02); a03 = wred(a03);
            a10 = wred(a10); a11 = wred(a11); a12 = wred(a12); a13 = wred(a13);

            if (lane == 0) {
                const float v0 = a00 + cb0, v1 = a01 + cb1;
                const float v2 = a02 + cb2, v3 = a03 + cb3;
                ((float4*)fN)[b0 * S + (s0 - 1)] = make_float4(v0, v1, v2, v3);
                const int tb0 = b0 * 4 * S + (s0 - 1);
                fT[tb0 + 0 * S] = v0; fT[tb0 + 1 * S] = v1;
                fT[tb0 + 2 * S] = v2; fT[tb0 + 3 * S] = v3;
                const float u0 = a10 + cb0, u1 = a11 + cb1;
                const float u2 = a12 + cb2, u3 = a13 + cb3;
                ((float4*)fN)[b1 * S + (s1 - 1)] = make_float4(u0, u1, u2, u3);
                const int tb1 = b1 * 4 * S + (s1 - 1);
                fT[tb1 + 0 * S] = u0; fT[tb1 + 1 * S] = u1;
                fT[tb1 + 2 * S] = u2; fT[tb1 + 3 * S] = u3;
            }
        }
    }

    __threadfence();                 // release feats device-wide
    cg::this_grid().sync();          // grid barrier (+ acquire)

    // ===================== Phase 2 =====================
    if (blk < 64) {
        // ================= Z-block: batch b =================
        const int b = blk;
        float* sf  = smemf;            // 2048 floats
        float* C   = smemf + 2048;     // 64 chunk matrices x 16
        float* red = smemf + 3072;     // 4 floats

        float tr[16];
        #pragma unroll
        for (int i = 0; i < 16; ++i) tr[i] = trans[i];

        {   // stage feats[b] (normal layout)
            float4* sf4 = (float4*)sf;
            const float4* src4 = (const float4*)(ws + WS_FEATS) + b * 512;
            sf4[tid] = src4[tid];
            sf4[tid + 256] = src4[tid + 256];
        }

        // ---- fc2 logits for this batch (waves 0,1) ----
        if (tid < 128) {
            const int wv = tid >> 6;       // 0 or 1
            const float4* e4 = (const float4*)emb + (size_t)b * S1 * (H / 4);
            const float4* w4 = (const float4*)fc2_W + wv * 192;
            float acc = 0.f;
            #pragma unroll
            for (int k = 0; k < 3; ++k) {
                const float4 e = e4[lane + 64 * k];
                const float4 w = w4[lane + 64 * k];
                acc += dot4(e, w);
            }
            acc = wred(acc);
            if (lane == 0) {
                ws[WS_LOGITS + 2 * b + wv] = acc + fc2_b[wv];
                __threadfence();
            }
        }
        __syncthreads();

        // ---- gold score + tags echo ----
        float g = 0.f;
        #pragma unroll
        for (int u = 0; u < 2; ++u) {
            const int t   = 2 * tid + u;
            const int tag = ans[b * S1 + 1 + t];
            out[OUT_TAGS + b * S + t] = (float)tag;
            g += sf[t * 4 + tag];
            g += (t == 0) ? tr[START * 4 + tag] : tr[ans[b * S1 + t] * 4 + tag];
            if (t == S - 1) g += tr[tag * 4 + STOP];
        }
        #pragma unroll
        for (int m = 32; m; m >>= 1) g += __shfl_xor(g, m);
        if ((tid & 63) == 0) red[tid >> 6] = g;

        // ---- Phase A: chunk matrices, thread (c,jr) owns row jr of chunk c ----
        const int c  = tid >> 2;
        const int jr = tid & 3;
        const int t0 = c ? 8 * c : 1;
        float rl[4];
        #pragma unroll
        for (int i = 0; i < 4; ++i) rl[i] = tr[jr * 4 + i] + sf[t0 * 4 + i];
        for (int t = t0 + 1; t <= 8 * c + 7; ++t) {
            const float f0 = sf[t*4+0], f1 = sf[t*4+1], f2 = sf[t*4+2], f3 = sf[t*4+3];
            float nr[4];
            #pragma unroll
            for (int i = 0; i < 4; ++i)
                nr[i] = lse4(rl[0] + tr[0*4+i], rl[1] + tr[1*4+i],
                             rl[2] + tr[2*4+i], rl[3] + tr[3*4+i]);
            rl[0] = nr[0] + f0; rl[1] = nr[1] + f1;
            rl[2] = nr[2] + f2; rl[3] = nr[3] + f3;
        }
        ((float4*)C)[c * 4 + jr] = make_float4(rl[0], rl[1], rl[2], rl[3]);
        __syncthreads();

        // ---- Hillis-Steele inclusive scan over 64 chunk matrices ----
        for (int d = 1; d <= 32; d <<= 1) {
            const int cs = (c >= d) ? (c - d) : c;
            float4 ar = ((float4*)C)[cs * 4 + jr];
            float4 b0 = ((float4*)C)[c * 4 + 0];
            float4 b1 = ((float4*)C)[c * 4 + 1];
            float4 b2 = ((float4*)C)[c * 4 + 2];
            float4 b3 = ((float4*)C)[c * 4 + 3];
            __syncthreads();
            if (c >= d) {
                float4 nr;
                nr.x = lse4(ar.x + b0.x, ar.y + b1.x, ar.z + b2.x, ar.w + b3.x);
                nr.y = lse4(ar.x + b0.y, ar.y + b1.y, ar.z + b2.y, ar.w + b3.y);
                nr.z = lse4(ar.x + b0.z, ar.y + b1.z, ar.z + b2.z, ar.w + b3.z);
                nr.w = lse4(ar.x + b0.w, ar.y + b1.w, ar.z + b2.w, ar.w + b3.w);
                ((float4*)C)[c * 4 + jr] = nr;
            }
            __syncthreads();
        }

        if (tid == 0) {
            const float gold = red[0] + red[1] + red[2] + red[3];
            float a0k[4];
            #pragma unroll
            for (int k = 0; k < 4; ++k) a0k[k] = sf[k] + tr[START * 4 + k];
            const float* P = C + 63 * 16;   // P[k*4+i]
            float aN[4];
            #pragma unroll
            for (int i = 0; i < 4; ++i)
                aN[i] = lse4(a0k[0] + P[0*4+i], a0k[1] + P[1*4+i],
                             a0k[2] + P[2*4+i], a0k[3] + P[3*4+i]);
            const float Z = lse4(aN[0] + tr[0*4+STOP], aN[1] + tr[1*4+STOP],
                                 aN[2] + tr[2*4+STOP], aN[3] + tr[3*4+STOP]);
            ws[WS_ZG + b] = Z - gold;
            out[OUT_ISQA + b] = (float)isqa[b];
            __threadfence();                 // release zg before counter inc
            const int old = atomicAdd((int*)ws + WS_CNT, 1);
            isLast = (old == 63);
        }
        __syncthreads();

        // ---- finisher: last Z-block computes losses + isqa_pred ----
        if (isLast && tid < 64) {
            __threadfence();                 // acquire all blocks' zg/logits
            const float zg = ws[WS_ZG + tid];
            const float l0 = ws[WS_LOGITS + tid * 2 + 0];
            const float l1 = ws[WS_LOGITS + tid * 2 + 1];
            const float m  = fmaxf(l0, l1);
            const float lse = m + __logf(__expf(l0 - m) + __expf(l1 - m));
            const int   y   = isqa[tid];
            const float li  = lse - (y ? l1 : l0);
            float s1 = zg, s2 = li;
            #pragma unroll
            for (int d = 32; d; d >>= 1) {
                s1 += __shfl_xor(s1, d);
                s2 += __shfl_xor(s2, d);
            }
            out[OUT_ISQA_PRED + tid] = (l1 > l0) ? 1.0f : 0.0f;
            if (tid == 0) {
                out[OUT_CRF_LOSS]  = s1 * (1.0f / 64.0f);
                out[OUT_ISQA_LOSS] = s2 * (1.0f / 64.0f);
            }
        }
    } else if (blk < 80) {
        // ================= V-block: batches 4*(blk-64) .. +3 =================
        const int bv = blk - 64;
        float* sfT = smemf;                                    // 8192 + 16 pad
        {   // stage transposed feats for 4 batches
            float4* d4 = (float4*)sfT;
            const float4* s4 = (const float4*)(ws + WS_FEATST) + bv * 4 * 512;
            #pragma unroll
            for (int n = 0; n < 8; ++n) d4[tid + 256 * n] = s4[tid + 256 * n];
        }
        if (tid < 4) ((float4*)(sfT + 8192))[tid & 3] =
            make_float4(0.f, 0.f, 0.f, 0.f);                   // pad
        __syncthreads();

        const int w    = tid >> 6;
        const int j    = lane & 3;
        const int b    = bv * 4 + w;
        const int sh8j = 8 * j;

        const float tc0 = trans[0*4+j], tc1 = trans[1*4+j];
        const float tc2 = trans[2*4+j], tc3 = trans[3*4+j];
        const float tSj = trans[START*4+j];
        const float tjs = trans[j*4 + STOP];

        const float4* colT4 = (const float4*)(sfT + w * 2048 + j * 512);

        unsigned int wk[8] = {0, 0, 0, 0, 0, 0, 0, 0};
        float4 A  = colT4[0];        // t 0..3
        float4 Bq = colT4[1];        // t 4..7
        float4 B2 = colT4[2];        // t 8..11
        float d = A.x + tSj;
        {
            const unsigned int W1 = vstep(d, A.y, tc0, tc1, tc2, tc3, sh8j);
            const unsigned int W2 = vstep(d, A.z, tc0, tc1, tc2, tc3, sh8j);
            const unsigned int W3 = vstep(d, A.w, tc0, tc1, tc2, tc3, sh8j);
            if (lane == 0) { wk[0] = 0x03020100u; wk[1] = W1; wk[2] = W2; wk[3] = W3; }
        }
        for (int g = 1; g < 128; ++g) {
            const float4 Cq = colT4[g + 2];   // prefetch (pad covers g>=126)
            const unsigned int W0 = vstep(d, Bq.x, tc0, tc1, tc2, tc3, sh8j);
            const unsigned int W1 = vstep(d, Bq.y, tc0, tc1, tc2, tc3, sh8j);
            const unsigned int W2 = vstep(d, Bq.z, tc0, tc1, tc2, tc3, sh8j);
            const unsigned int W3 = vstep(d, Bq.w, tc0, tc1, tc2, tc3, sh8j);
            if (g == 2 * lane)     { wk[0] = W0; wk[1] = W1; wk[2] = W2; wk[3] = W3; }
            if (g == 2 * lane + 1) { wk[4] = W0; wk[5] = W1; wk[6] = W2; wk[7] = W3; }
            Bq = B2; B2 = Cq;
        }

        // last_tag (first-index-wins argmax over states)
        const float vj = d + tjs;
        const float z0 = dppf<0x00>(vj), z1 = dppf<0x55>(vj);
        const float z2 = dppf<0xAA>(vj), z3 = dppf<0xFF>(vj);
        float m01 = z0; unsigned int i01 = 0;
        if (z1 > m01) { m01 = z1; i01 = 1; }
        float m23 = z2; unsigned int i23 = 2;
        if (z3 > m23) { m23 = z3; i23 = 3; }
        const unsigned int lt = (m23 > m01) ? i23 : i01;

        // backtrack: chunk map composition via v_perm_b32 (all in registers)
        unsigned int G = wk[7];
        #pragma unroll
        for (int k = 6; k >= 0; --k)
            G = __builtin_amdgcn_perm(0u, wk[k], G);     // f_k ∘ G
        unsigned int Sm = G;
        #pragma unroll
        for (int dd = 1; dd < 64; dd <<= 1) {
            const int srcl = lane + dd;
            const unsigned int oth = __shfl(Sm, (srcl < 64) ? srcl : 63);
            if (srcl < 64) Sm = __builtin_amdgcn_perm(0u, Sm, oth);  // Sm ∘ oth
        }
        unsigned int emap = __shfl(Sm, (lane < 63) ? lane + 1 : 63);
        if (lane == 63) emap = 0x03020100u;
        unsigned int cur = (emap >> (8 * lt)) & 3u;

        float tg[8];
        tg[7] = (float)cur;
        #pragma unroll
        for (int k = 7; k >= 1; --k) {
            cur = (wk[k] >> (8 * cur)) & 3u;
            tg[k - 1] = (float)cur;
        }
        float4* op = (float4*)(out + OUT_CRF_PRED + b * S + lane * 8);
        op[0] = make_float4(tg[0], tg[1], tg[2], tg[3]);
        op[1] = make_float4(tg[4], tg[5], tg[6], tg[7]);
    }
}

// ---------------------------------------------------------------------------
extern "C" void kernel_launch(void* const* d_in, const int* in_sizes, int n_in,
                              void* d_out, int out_size, void* d_ws, size_t ws_size,
                              hipStream_t stream)
{
    const int*   ans    = (const int*)d_in[1];
    const int*   isqa   = (const int*)d_in[2];
    const float* emb    = (const float*)d_in[0];
    const float* fc2_W  = (const float*)d_in[3];
    const float* fc2_b  = (const float*)d_in[4];
    const float* crf_W  = (const float*)d_in[5];
    const float* crf_b  = (const float*)d_in[6];
    const float* trans  = (const float*)d_in[7];
    float* out = (float*)d_out;
    float* ws  = (float*)d_ws;

    void* args[] = {(void*)&ans, (void*)&isqa, (void*)&emb,
                    (void*)&fc2_W, (void*)&fc2_b, (void*)&crf_W, (void*)&crf_b,
                    (void*)&trans, (void*)&ws, (void*)&out};
    hipLaunchCooperativeKernel((void*)fused_kernel, dim3(512), dim3(256),
                               args, 0, stream);
}

// Round 6
// 224.320 us; speedup vs baseline: 1.3908x; 1.3908x over previous
//
#include <hip/hip_runtime.h>
#include <math.h>

// Problem constants
#define B     64
#define S1    513
#define S     512
#define H     768
#define T     4
#define START 2
#define STOP  3

// d_out layout (floats), reference tuple order:
// (isqa_pred[64,1], crf_pred[64,512], isqa_loss, crf_loss, tags[64,512], IsQA[64,1])
#define OUT_ISQA_PRED 0
#define OUT_CRF_PRED  64
#define OUT_ISQA_LOSS 32832
#define OUT_CRF_LOSS  32833
#define OUT_TAGS      32834
#define OUT_ISQA      65602

// ws layout (floats)
#define WS_FEATS  0                  // [B][S][T]  normal layout
#define WS_LOGITS (B*S*T)            // 131072: [B][2]
#define WS_ZG     (B*S*T + 2*B)      // 131200: [B]
#define WS_CNT    (B*S*T + 3*B)      // 131264: int counter
#define WS_FEATST 131280             // [B][T][S] transposed layout

// ---------------------------------------------------------------------------
// DPP helpers (quad_perm broadcasts/butterflies within groups of 4 lanes)
// ---------------------------------------------------------------------------
template<int CTRL>
__device__ __forceinline__ float dppf(float x) {
    int v = __builtin_amdgcn_update_dpp(__builtin_bit_cast(int, x),
                                        __builtin_bit_cast(int, x),
                                        CTRL, 0xF, 0xF, false);
    return __builtin_bit_cast(float, v);
}
template<int CTRL>
__device__ __forceinline__ int dppi(int x) {
    return __builtin_amdgcn_update_dpp(x, x, CTRL, 0xF, 0xF, false);
}

__device__ __forceinline__ float lse4(float x0, float x1, float x2, float x3) {
    float m = fmaxf(fmaxf(x0, x1), fmaxf(x2, x3));
    return m + __logf(__expf(x0 - m) + __expf(x1 - m) +
                      __expf(x2 - m) + __expf(x3 - m));
}

// full-wave sum reduction: DPP xor1/xor2 + shfl xor4..32 (result in all lanes)
__device__ __forceinline__ float wred(float a) {
    a += dppf<0xB1>(a); a += dppf<0x4E>(a);
    a += __shfl_xor(a, 4); a += __shfl_xor(a, 8);
    a += __shfl_xor(a, 16); a += __shfl_xor(a, 32);
    return a;
}

__device__ __forceinline__ float dot4(float4 e, float4 w) {
    return e.x * w.x + e.y * w.y + e.z * w.z + e.w * w.w;
}

// ---------------------------------------------------------------------------
// Kernel 1: feats = emb[:,1:] @ crf_W.T + crf_b  — thread-per-row GEMV.
// Lane = one emb row; 192 global dwordx4 loads per lane; crf_W read via
// wave-uniform indices -> scalar loads into SGPRs (no LDS, no butterflies).
// Grid 512 x 64: one wave per block, ~2 waves/CU, unroll-8 load pipelining.
// Stores coalesced (lane i -> consecutive float4 / consecutive dwords).
// ---------------------------------------------------------------------------
__global__ __launch_bounds__(64) void feats_kernel(
    const float* __restrict__ emb,
    const float* __restrict__ crf_W, const float* __restrict__ crf_b,
    float* __restrict__ ws)
{
    if (blockIdx.x == 0 && threadIdx.x == 0)
        ((int*)ws)[WS_CNT] = 0;      // zero crf completion counter

    const int lane = threadIdx.x;                    // 0..63
    const int r    = blockIdx.x * 64 + lane;         // 0..32767
    const int b    = r >> 9;
    const int s    = (r & 511) + 1;

    const float4* __restrict__ src4 =
        (const float4*)emb + (size_t)(b * S1 + s) * (H / 4);
    const float4* __restrict__ W4 = (const float4*)crf_W;   // [4][192], uniform

    float a0 = 0.f, a1 = 0.f, a2 = 0.f, a3 = 0.f;
    #pragma unroll 8
    for (int k = 0; k < 192; ++k) {
        const float4 e  = src4[k];
        const float4 w0 = W4[0 * 192 + k];   // wave-uniform -> SGPRs
        const float4 w1 = W4[1 * 192 + k];
        const float4 w2 = W4[2 * 192 + k];
        const float4 w3 = W4[3 * 192 + k];
        a0 += dot4(e, w0);
        a1 += dot4(e, w1);
        a2 += dot4(e, w2);
        a3 += dot4(e, w3);
    }

    const float v0 = a0 + crf_b[0];
    const float v1 = a1 + crf_b[1];
    const float v2 = a2 + crf_b[2];
    const float v3 = a3 + crf_b[3];

    float* __restrict__ fN = ws + WS_FEATS;
    float* __restrict__ fT = ws + WS_FEATST;
    ((float4*)fN)[b * S + (s - 1)] = make_float4(v0, v1, v2, v3);
    const int tb = b * 4 * S + (s - 1);
    fT[tb + 0 * S] = v0;
    fT[tb + 1 * S] = v1;
    fT[tb + 2 * S] = v2;
    fT[tb + 3 * S] = v3;
}

// ---------------------------------------------------------------------------
// Viterbi step: bit-exact value path (max of exact sums + add), first-index
// argmax; returns quad-packed map word (byte j = argmax for state j).
// ---------------------------------------------------------------------------
__device__ __forceinline__ unsigned int vstep(
    float& d, float fv,
    float tc0, float tc1, float tc2, float tc3, int sh8j)
{
    const float d0 = dppf<0x00>(d), d1 = dppf<0x55>(d);
    const float d2 = dppf<0xAA>(d), d3 = dppf<0xFF>(d);
    const float y0 = d0 + tc0, y1 = d1 + tc1;
    const float y2 = d2 + tc2, y3 = d3 + tc3;
    const float m01 = fmaxf(y0, y1), m23 = fmaxf(y2, y3);
    const int   i01 = (y1 > y0) ? 1 : 0;
    const int   i23 = (y3 > y2) ? 3 : 2;
    const int   bi  = (m23 > m01) ? i23 : i01;
    d = fmaxf(m01, m23) + fv;
    unsigned int mb = (unsigned int)bi << sh8j;      // byte slot j
    unsigned int t1 = mb | (unsigned int)dppi<0xB1>((int)mb);
    return t1 | (unsigned int)dppi<0x4E>((int)t1);
}

// ---------------------------------------------------------------------------
// Kernel 2: grid 80.
// Blocks 0..63 (Z): per-batch log-partition (chunked log-semiring scan), gold
//   score, tags echo, IsQA echo, fc2 logits; last block computes final losses.
// Blocks 64..79 (V): 4 batches each; bit-exact sequential Viterbi with
//   transposed-LDS b128 feats prefetch + packed backpointers; map-composition
//   backtrack.
// ---------------------------------------------------------------------------
__global__ __launch_bounds__(256) void crf_kernel(
    const int* __restrict__ ans, const int* __restrict__ isqa,
    const float* __restrict__ emb,
    const float* __restrict__ fc2_W, const float* __restrict__ fc2_b,
    const float* __restrict__ trans,
    float* __restrict__ ws, float* __restrict__ out)
{
    __shared__ float smemf[10784];   // V: sfT 8192 + pad 16 + bpw 2048 words
    __shared__ int isLast;
    const int tid = threadIdx.x;
    const int blk = blockIdx.x;

    if (blk < 64) {
        // ================= Z-block: batch b =================
        const int b = blk;
        float* sf  = smemf;            // 2048 floats
        float* C   = smemf + 2048;     // 64 chunk matrices x 16
        float* red = smemf + 3072;     // 4 floats

        float tr[16];
        #pragma unroll
        for (int i = 0; i < 16; ++i) tr[i] = trans[i];

        {   // stage feats[b] (normal layout)
            float4* sf4 = (float4*)sf;
            const float4* src4 = (const float4*)(ws + WS_FEATS) + b * 512;
            sf4[tid] = src4[tid];
            sf4[tid + 256] = src4[tid + 256];
        }

        // ---- fc2 logits for this batch (waves 0,1), independent of LDS ----
        if (tid < 128) {
            const int wv   = tid >> 6;       // 0 or 1
            const int lane = tid & 63;
            const float4* e4 = (const float4*)emb + (size_t)b * S1 * (H / 4);
            const float4* w4 = (const float4*)fc2_W + wv * 192;
            float acc = 0.f;
            #pragma unroll
            for (int k = 0; k < 3; ++k) {
                const float4 e = e4[lane + 64 * k];
                const float4 w = w4[lane + 64 * k];
                acc += dot4(e, w);
            }
            acc = wred(acc);
            if (lane == 0) {
                ws[WS_LOGITS + 2 * b + wv] = acc + fc2_b[wv];
                __threadfence();             // release this store device-wide
            }
        }
        __syncthreads();

        // ---- gold score + tags echo ----
        float g = 0.f;
        #pragma unroll
        for (int u = 0; u < 2; ++u) {
            const int t   = 2 * tid + u;
            const int tag = ans[b * S1 + 1 + t];
            out[OUT_TAGS + b * S + t] = (float)tag;
            g += sf[t * 4 + tag];
            g += (t == 0) ? tr[START * 4 + tag] : tr[ans[b * S1 + t] * 4 + tag];
            if (t == S - 1) g += tr[tag * 4 + STOP];
        }
        #pragma unroll
        for (int m = 32; m; m >>= 1) g += __shfl_xor(g, m);
        if ((tid & 63) == 0) red[tid >> 6] = g;

        // ---- Phase A: chunk matrices, thread (c,jr) owns row jr of chunk c ----
        const int c  = tid >> 2;
        const int jr = tid & 3;
        const int t0 = c ? 8 * c : 1;
        float rl[4];
        #pragma unroll
        for (int i = 0; i < 4; ++i) rl[i] = tr[jr * 4 + i] + sf[t0 * 4 + i];
        for (int t = t0 + 1; t <= 8 * c + 7; ++t) {
            const float f0 = sf[t*4+0], f1 = sf[t*4+1], f2 = sf[t*4+2], f3 = sf[t*4+3];
            float nr[4];
            #pragma unroll
            for (int i = 0; i < 4; ++i)
                nr[i] = lse4(rl[0] + tr[0*4+i], rl[1] + tr[1*4+i],
                             rl[2] + tr[2*4+i], rl[3] + tr[3*4+i]);
            rl[0] = nr[0] + f0; rl[1] = nr[1] + f1;
            rl[2] = nr[2] + f2; rl[3] = nr[3] + f3;
        }
        ((float4*)C)[c * 4 + jr] = make_float4(rl[0], rl[1], rl[2], rl[3]);
        __syncthreads();

        // ---- Hillis-Steele inclusive scan over 64 chunk matrices ----
        for (int d = 1; d <= 32; d <<= 1) {
            const int cs = (c >= d) ? (c - d) : c;
            float4 ar = ((float4*)C)[cs * 4 + jr];
            float4 b0 = ((float4*)C)[c * 4 + 0];
            float4 b1 = ((float4*)C)[c * 4 + 1];
            float4 b2 = ((float4*)C)[c * 4 + 2];
            float4 b3 = ((float4*)C)[c * 4 + 3];
            __syncthreads();
            if (c >= d) {
                float4 nr;
                nr.x = lse4(ar.x + b0.x, ar.y + b1.x, ar.z + b2.x, ar.w + b3.x);
                nr.y = lse4(ar.x + b0.y, ar.y + b1.y, ar.z + b2.y, ar.w + b3.y);
                nr.z = lse4(ar.x + b0.z, ar.y + b1.z, ar.z + b2.z, ar.w + b3.z);
                nr.w = lse4(ar.x + b0.w, ar.y + b1.w, ar.z + b2.w, ar.w + b3.w);
                ((float4*)C)[c * 4 + jr] = nr;
            }
            __syncthreads();
        }

        if (tid == 0) {
            const float gold = red[0] + red[1] + red[2] + red[3];
            float a0k[4];
            #pragma unroll
            for (int k = 0; k < 4; ++k) a0k[k] = sf[k] + tr[START * 4 + k];
            const float* P = C + 63 * 16;   // P[k*4+i]
            float aN[4];
            #pragma unroll
            for (int i = 0; i < 4; ++i)
                aN[i] = lse4(a0k[0] + P[0*4+i], a0k[1] + P[1*4+i],
                             a0k[2] + P[2*4+i], a0k[3] + P[3*4+i]);
            const float Z = lse4(aN[0] + tr[0*4+STOP], aN[1] + tr[1*4+STOP],
                                 aN[2] + tr[2*4+STOP], aN[3] + tr[3*4+STOP]);
            ws[WS_ZG + b] = Z - gold;
            out[OUT_ISQA + b] = (float)isqa[b];
            __threadfence();                 // release zg before counter inc
            const int old = atomicAdd((int*)ws + WS_CNT, 1);
            isLast = (old == 63);
        }
        __syncthreads();

        // ---- finisher: last Z-block computes losses + isqa_pred ----
        if (isLast && tid < 64) {
            __threadfence();                 // acquire all blocks' zg/logits
            const float zg = ws[WS_ZG + tid];
            const float l0 = ws[WS_LOGITS + tid * 2 + 0];
            const float l1 = ws[WS_LOGITS + tid * 2 + 1];
            const float m  = fmaxf(l0, l1);
            const float lse = m + __logf(__expf(l0 - m) + __expf(l1 - m));
            const int   y   = isqa[tid];
            const float li  = lse - (y ? l1 : l0);
            float s1 = zg, s2 = li;
            #pragma unroll
            for (int d = 32; d; d >>= 1) {
                s1 += __shfl_xor(s1, d);
                s2 += __shfl_xor(s2, d);
            }
            out[OUT_ISQA_PRED + tid] = (l1 > l0) ? 1.0f : 0.0f;
            if (tid == 0) {
                out[OUT_CRF_LOSS]  = s1 * (1.0f / 64.0f);
                out[OUT_ISQA_LOSS] = s2 * (1.0f / 64.0f);
            }
        }
    } else {
        // ================= V-block: batches 4*(blk-64) .. +3 =================
        const int bv = blk - 64;
        float* sfT = smemf;                                    // 8192 + 16 pad
        unsigned int* bpw = (unsigned int*)(smemf + 8208);     // 4 x 512 words
        {   // stage transposed feats for 4 batches
            float4* d4 = (float4*)sfT;
            const float4* s4 = (const float4*)(ws + WS_FEATST) + bv * 4 * 512;
            #pragma unroll
            for (int n = 0; n < 8; ++n) d4[tid + 256 * n] = s4[tid + 256 * n];
        }
        if (tid < 4) ((float4*)(sfT + 8192))[tid & 3] =
            make_float4(0.f, 0.f, 0.f, 0.f);                   // pad
        __syncthreads();

        const int w    = tid >> 6;
        const int lane = tid & 63;
        const int j    = lane & 3;
        const int b    = bv * 4 + w;
        const int sh8j = 8 * j;

        const float tc0 = trans[0*4+j], tc1 = trans[1*4+j];
        const float tc2 = trans[2*4+j], tc3 = trans[3*4+j];
        const float tSj = trans[START*4+j];
        const float tjs = trans[j*4 + STOP];

        const float4* colT4 = (const float4*)(sfT + w * 2048 + j * 512);
        uint4* bpq = (uint4*)(bpw + w * 512);

        float4 A  = colT4[0];        // t 0..3
        float4 Bq = colT4[1];        // t 4..7
        float4 B2 = colT4[2];        // t 8..11
        float d = A.x + tSj;
        {
            const unsigned int W1 = vstep(d, A.y, tc0, tc1, tc2, tc3, sh8j);
            const unsigned int W2 = vstep(d, A.z, tc0, tc1, tc2, tc3, sh8j);
            const unsigned int W3 = vstep(d, A.w, tc0, tc1, tc2, tc3, sh8j);
            if (lane == 0) bpq[0] = make_uint4(0x03020100u, W1, W2, W3);
        }
        for (int g = 1; g < 128; ++g) {
            const float4 Cq = colT4[g + 2];   // prefetch (pad covers g>=126)
            const unsigned int W0 = vstep(d, Bq.x, tc0, tc1, tc2, tc3, sh8j);
            const unsigned int W1 = vstep(d, Bq.y, tc0, tc1, tc2, tc3, sh8j);
            const unsigned int W2 = vstep(d, Bq.z, tc0, tc1, tc2, tc3, sh8j);
            const unsigned int W3 = vstep(d, Bq.w, tc0, tc1, tc2, tc3, sh8j);
            if (lane == 0) bpq[g] = make_uint4(W0, W1, W2, W3);
            Bq = B2; B2 = Cq;
        }

        // last_tag (first-index-wins argmax over states)
        const float vj = d + tjs;
        const float z0 = dppf<0x00>(vj), z1 = dppf<0x55>(vj);
        const float z2 = dppf<0xAA>(vj), z3 = dppf<0xFF>(vj);
        float m01 = z0; unsigned int i01 = 0;
        if (z1 > m01) { m01 = z1; i01 = 1; }
        float m23 = z2; unsigned int i23 = 2;
        if (z3 > m23) { m23 = z3; i23 = 3; }
        const unsigned int lt = (m23 > m01) ? i23 : i01;

        __syncthreads();

        // backtrack: chunk map composition via v_perm_b32
        const uint4 wv0 = bpq[lane * 2 + 0];   // t = 8L..8L+3
        const uint4 wv1 = bpq[lane * 2 + 1];   // t = 8L+4..8L+7
        unsigned int wk[8] = {wv0.x, wv0.y, wv0.z, wv0.w, wv1.x, wv1.y, wv1.z, wv1.w};
        unsigned int G = wk[7];
        #pragma unroll
        for (int k = 6; k >= 0; --k)
            G = __builtin_amdgcn_perm(0u, wk[k], G);     // f_k ∘ G
        unsigned int Sm = G;
        #pragma unroll
        for (int dd = 1; dd < 64; dd <<= 1) {
            const int srcl = lane + dd;
            const unsigned int oth = __shfl(Sm, (srcl < 64) ? srcl : 63);
            if (srcl < 64) Sm = __builtin_amdgcn_perm(0u, Sm, oth);  // Sm ∘ oth
        }
        unsigned int emap = __shfl(Sm, (lane < 63) ? lane + 1 : 63);
        if (lane == 63) emap = 0x03020100u;
        unsigned int cur = (emap >> (8 * lt)) & 3u;

        float tg[8];
        tg[7] = (float)cur;
        #pragma unroll
        for (int k = 7; k >= 1; --k) {
            cur = (wk[k] >> (8 * cur)) & 3u;
            tg[k - 1] = (float)cur;
        }
        float4* op = (float4*)(out + OUT_CRF_PRED + b * S + lane * 8);
        op[0] = make_float4(tg[0], tg[1], tg[2], tg[3]);
        op[1] = make_float4(tg[4], tg[5], tg[6], tg[7]);
    }
}

// ---------------------------------------------------------------------------
extern "C" void kernel_launch(void* const* d_in, const int* in_sizes, int n_in,
                              void* d_out, int out_size, void* d_ws, size_t ws_size,
                              hipStream_t stream)
{
    const float* emb    = (const float*)d_in[0];
    const int*   ans    = (const int*)d_in[1];
    const int*   isqa   = (const int*)d_in[2];
    const float* fc2_W  = (const float*)d_in[3];
    const float* fc2_b  = (const float*)d_in[4];
    const float* crf_W  = (const float*)d_in[5];
    const float* crf_b  = (const float*)d_in[6];
    const float* trans  = (const float*)d_in[7];
    float* out = (float*)d_out;
    float* ws  = (float*)d_ws;

    feats_kernel<<<512, 64, 0, stream>>>(emb, crf_W, crf_b, ws);
    crf_kernel<<<80, 256, 0, stream>>>(ans, isqa, emb, fc2_W, fc2_b, trans, ws, out);
}

// Round 7
// 198.878 us; speedup vs baseline: 1.5687x; 1.1279x over previous
//
#include <hip/hip_runtime.h>
#include <math.h>

// Problem constants
#define B     64
#define S1    513
#define S     512
#define H     768
#define T     4
#define START 2
#define STOP  3

// d_out layout (floats), reference tuple order:
// (isqa_pred[64,1], crf_pred[64,512], isqa_loss, crf_loss, tags[64,512], IsQA[64,1])
#define OUT_ISQA_PRED 0
#define OUT_CRF_PRED  64
#define OUT_ISQA_LOSS 32832
#define OUT_CRF_LOSS  32833
#define OUT_TAGS      32834
#define OUT_ISQA      65602

// ws layout (floats)
#define WS_FEATS  0                  // [B][S][T]  normal layout
#define WS_LOGITS (B*S*T)            // 131072: [B][2]
#define WS_ZG     (B*S*T + 2*B)      // 131200: [B]
#define WS_CNT    (B*S*T + 3*B)      // 131264: int counter
#define WS_FEATST 131280             // [B][T][S] transposed layout

// feats tiling
#define RB   64     // rows per block
#define KC   16     // K-chunk in float4 (64 floats)
#define NC   12     // chunks: 12 * 64 = 768
#define RS   17     // LDS row stride in float4 (pad 1 -> mild conflicts only)

// ---------------------------------------------------------------------------
// DPP helpers (quad_perm broadcasts/butterflies within groups of 4 lanes)
// ---------------------------------------------------------------------------
template<int CTRL>
__device__ __forceinline__ float dppf(float x) {
    int v = __builtin_amdgcn_update_dpp(__builtin_bit_cast(int, x),
                                        __builtin_bit_cast(int, x),
                                        CTRL, 0xF, 0xF, false);
    return __builtin_bit_cast(float, v);
}
template<int CTRL>
__device__ __forceinline__ int dppi(int x) {
    return __builtin_amdgcn_update_dpp(x, x, CTRL, 0xF, 0xF, false);
}

__device__ __forceinline__ float lse4(float x0, float x1, float x2, float x3) {
    float m = fmaxf(fmaxf(x0, x1), fmaxf(x2, x3));
    return m + __logf(__expf(x0 - m) + __expf(x1 - m) +
                      __expf(x2 - m) + __expf(x3 - m));
}

// full-wave sum reduction: DPP xor1/xor2 + shfl xor4..32 (result in all lanes)
__device__ __forceinline__ float wred(float a) {
    a += dppf<0xB1>(a); a += dppf<0x4E>(a);
    a += __shfl_xor(a, 4); a += __shfl_xor(a, 8);
    a += __shfl_xor(a, 16); a += __shfl_xor(a, 32);
    return a;
}

__device__ __forceinline__ float dot4(float4 e, float4 w) {
    return e.x * w.x + e.y * w.y + e.z * w.z + e.w * w.w;
}

// ---------------------------------------------------------------------------
// Kernel 1: feats = emb[:,1:] @ crf_W.T + crf_b  — LDS-tiled GEMV.
// 512 blocks x 256 threads, 64 rows/block, K in 12 chunks of 64 floats,
// double-buffered LDS. Staging: 16 threads per row-chunk (256 B contiguous
// segments). Compute: thread = (row, quarter); weight reads are wave-uniform
// (LDS broadcast). Cross-quarter reduce via one LDS round.
// ---------------------------------------------------------------------------
__global__ __launch_bounds__(256) void feats_kernel(
    const float* __restrict__ emb,
    const float* __restrict__ crf_W, const float* __restrict__ crf_b,
    float* __restrict__ ws)
{
    __shared__ float4 wlds[4 * 192];          // 12 KB: crf_W as float4
    __shared__ float4 buf[2][RB * RS];        // 34 KB: double-buffered row tiles
    __shared__ float4 red[3][RB];             // 3 KB: cross-quarter partials

    const int tid = threadIdx.x;
    const int blk = blockIdx.x;
    if (blk == 0 && tid == 0) ((int*)ws)[WS_CNT] = 0;

    // stage weights (coalesced, once)
    {
        const float4* W4 = (const float4*)crf_W;
        wlds[tid]       = W4[tid];
        wlds[tid + 256] = W4[tid + 256];
        wlds[tid + 512] = W4[tid + 512];
    }

    // staging role: thread t covers rows r16+16p (p=0..3), float4 slot s16
    const int s16 = tid & 15;
    const int r16 = tid >> 4;
    const float4* __restrict__ emb4 = (const float4*)emb;
    size_t sbase[4];
    #pragma unroll
    for (int p = 0; p < 4; ++p) {
        const int row = blk * RB + r16 + 16 * p;
        const int b   = row >> 9;
        const int s   = (row & 511) + 1;
        sbase[p] = (size_t)(b * S1 + s) * (H / 4) + s16;
    }

    // compute role: thread t owns row rb, quarter q
    const int rb = tid & 63;
    const int q  = tid >> 6;

    // prologue: stage chunk 0
    #pragma unroll
    for (int p = 0; p < 4; ++p)
        buf[0][(r16 + 16 * p) * RS + s16] = emb4[sbase[p]];
    __syncthreads();

    float a0 = 0.f, a1 = 0.f, a2 = 0.f, a3 = 0.f;
    int pb = 0;
    for (int c = 0; c < NC; ++c) {
        if (c + 1 < NC) {
            #pragma unroll
            for (int p = 0; p < 4; ++p)
                buf[pb ^ 1][(r16 + 16 * p) * RS + s16] =
                    emb4[sbase[p] + (size_t)(c + 1) * KC];
        }
        const float4* __restrict__ myrow = &buf[pb][rb * RS + q * 4];
        const float4* __restrict__ w0 = &wlds[0 * 192 + c * 16 + q * 4];
        const float4* __restrict__ w1 = &wlds[1 * 192 + c * 16 + q * 4];
        const float4* __restrict__ w2 = &wlds[2 * 192 + c * 16 + q * 4];
        const float4* __restrict__ w3 = &wlds[3 * 192 + c * 16 + q * 4];
        #pragma unroll
        for (int i = 0; i < 4; ++i) {
            const float4 e = myrow[i];
            a0 += dot4(e, w0[i]);
            a1 += dot4(e, w1[i]);
            a2 += dot4(e, w2[i]);
            a3 += dot4(e, w3[i]);
        }
        __syncthreads();
        pb ^= 1;
    }

    // cross-quarter reduce
    if (q != 0) red[q - 1][rb] = make_float4(a0, a1, a2, a3);
    __syncthreads();
    if (q == 0) {
        #pragma unroll
        for (int k = 0; k < 3; ++k) {
            const float4 r = red[k][rb];
            a0 += r.x; a1 += r.y; a2 += r.z; a3 += r.w;
        }
        const int row = blk * RB + rb;
        const int b   = row >> 9;
        const int s   = (row & 511) + 1;
        const float v0 = a0 + crf_b[0];
        const float v1 = a1 + crf_b[1];
        const float v2 = a2 + crf_b[2];
        const float v3 = a3 + crf_b[3];
        float* __restrict__ fN = ws + WS_FEATS;
        float* __restrict__ fT = ws + WS_FEATST;
        ((float4*)fN)[b * S + (s - 1)] = make_float4(v0, v1, v2, v3);
        const int tb = b * 4 * S + (s - 1);
        fT[tb + 0 * S] = v0;
        fT[tb + 1 * S] = v1;
        fT[tb + 2 * S] = v2;
        fT[tb + 3 * S] = v3;
    }
}

// ---------------------------------------------------------------------------
// Viterbi step: bit-exact value path (max of exact sums + add), first-index
// argmax; returns quad-packed map word (byte j = argmax for state j).
// ---------------------------------------------------------------------------
__device__ __forceinline__ unsigned int vstep(
    float& d, float fv,
    float tc0, float tc1, float tc2, float tc3, int sh8j)
{
    const float d0 = dppf<0x00>(d), d1 = dppf<0x55>(d);
    const float d2 = dppf<0xAA>(d), d3 = dppf<0xFF>(d);
    const float y0 = d0 + tc0, y1 = d1 + tc1;
    const float y2 = d2 + tc2, y3 = d3 + tc3;
    const float m01 = fmaxf(y0, y1), m23 = fmaxf(y2, y3);
    const int   i01 = (y1 > y0) ? 1 : 0;
    const int   i23 = (y3 > y2) ? 3 : 2;
    const int   bi  = (m23 > m01) ? i23 : i01;
    d = fmaxf(m01, m23) + fv;
    unsigned int mb = (unsigned int)bi << sh8j;      // byte slot j
    unsigned int t1 = mb | (unsigned int)dppi<0xB1>((int)mb);
    return t1 | (unsigned int)dppi<0x4E>((int)t1);
}

// ---------------------------------------------------------------------------
// Kernel 2: grid 80.
// Blocks 0..63 (Z): per-batch log-partition (chunked log-semiring scan), gold
//   score, tags echo, IsQA echo, fc2 logits; last block computes final losses.
// Blocks 64..79 (V): 4 batches each; bit-exact sequential Viterbi with
//   transposed-LDS b128 feats prefetch + packed backpointers; map-composition
//   backtrack.
// ---------------------------------------------------------------------------
__global__ __launch_bounds__(256) void crf_kernel(
    const int* __restrict__ ans, const int* __restrict__ isqa,
    const float* __restrict__ emb,
    const float* __restrict__ fc2_W, const float* __restrict__ fc2_b,
    const float* __restrict__ trans,
    float* __restrict__ ws, float* __restrict__ out)
{
    __shared__ float smemf[10784];   // V: sfT 8192 + pad 16 + bpw 2048 words
    __shared__ int isLast;
    const int tid = threadIdx.x;
    const int blk = blockIdx.x;

    if (blk < 64) {
        // ================= Z-block: batch b =================
        const int b = blk;
        float* sf  = smemf;            // 2048 floats
        float* C   = smemf + 2048;     // 64 chunk matrices x 16
        float* red = smemf + 3072;     // 4 floats

        float tr[16];
        #pragma unroll
        for (int i = 0; i < 16; ++i) tr[i] = trans[i];

        {   // stage feats[b] (normal layout)
            float4* sf4 = (float4*)sf;
            const float4* src4 = (const float4*)(ws + WS_FEATS) + b * 512;
            sf4[tid] = src4[tid];
            sf4[tid + 256] = src4[tid + 256];
        }

        // ---- fc2 logits for this batch (waves 0,1), independent of LDS ----
        if (tid < 128) {
            const int wv   = tid >> 6;       // 0 or 1
            const int lane = tid & 63;
            const float4* e4 = (const float4*)emb + (size_t)b * S1 * (H / 4);
            const float4* w4 = (const float4*)fc2_W + wv * 192;
            float acc = 0.f;
            #pragma unroll
            for (int k = 0; k < 3; ++k) {
                const float4 e = e4[lane + 64 * k];
                const float4 w = w4[lane + 64 * k];
                acc += dot4(e, w);
            }
            acc = wred(acc);
            if (lane == 0) {
                ws[WS_LOGITS + 2 * b + wv] = acc + fc2_b[wv];
                __threadfence();             // release this store device-wide
            }
        }
        __syncthreads();

        // ---- gold score + tags echo ----
        float g = 0.f;
        #pragma unroll
        for (int u = 0; u < 2; ++u) {
            const int t   = 2 * tid + u;
            const int tag = ans[b * S1 + 1 + t];
            out[OUT_TAGS + b * S + t] = (float)tag;
            g += sf[t * 4 + tag];
            g += (t == 0) ? tr[START * 4 + tag] : tr[ans[b * S1 + t] * 4 + tag];
            if (t == S - 1) g += tr[tag * 4 + STOP];
        }
        #pragma unroll
        for (int m = 32; m; m >>= 1) g += __shfl_xor(g, m);
        if ((tid & 63) == 0) red[tid >> 6] = g;

        // ---- Phase A: chunk matrices, thread (c,jr) owns row jr of chunk c ----
        const int c  = tid >> 2;
        const int jr = tid & 3;
        const int t0 = c ? 8 * c : 1;
        float rl[4];
        #pragma unroll
        for (int i = 0; i < 4; ++i) rl[i] = tr[jr * 4 + i] + sf[t0 * 4 + i];
        for (int t = t0 + 1; t <= 8 * c + 7; ++t) {
            const float f0 = sf[t*4+0], f1 = sf[t*4+1], f2 = sf[t*4+2], f3 = sf[t*4+3];
            float nr[4];
            #pragma unroll
            for (int i = 0; i < 4; ++i)
                nr[i] = lse4(rl[0] + tr[0*4+i], rl[1] + tr[1*4+i],
                             rl[2] + tr[2*4+i], rl[3] + tr[3*4+i]);
            rl[0] = nr[0] + f0; rl[1] = nr[1] + f1;
            rl[2] = nr[2] + f2; rl[3] = nr[3] + f3;
        }
        ((float4*)C)[c * 4 + jr] = make_float4(rl[0], rl[1], rl[2], rl[3]);
        __syncthreads();

        // ---- Hillis-Steele inclusive scan over 64 chunk matrices ----
        for (int d = 1; d <= 32; d <<= 1) {
            const int cs = (c >= d) ? (c - d) : c;
            float4 ar = ((float4*)C)[cs * 4 + jr];
            float4 b0 = ((float4*)C)[c * 4 + 0];
            float4 b1 = ((float4*)C)[c * 4 + 1];
            float4 b2 = ((float4*)C)[c * 4 + 2];
            float4 b3 = ((float4*)C)[c * 4 + 3];
            __syncthreads();
            if (c >= d) {
                float4 nr;
                nr.x = lse4(ar.x + b0.x, ar.y + b1.x, ar.z + b2.x, ar.w + b3.x);
                nr.y = lse4(ar.x + b0.y, ar.y + b1.y, ar.z + b2.y, ar.w + b3.y);
                nr.z = lse4(ar.x + b0.z, ar.y + b1.z, ar.z + b2.z, ar.w + b3.z);
                nr.w = lse4(ar.x + b0.w, ar.y + b1.w, ar.z + b2.w, ar.w + b3.w);
                ((float4*)C)[c * 4 + jr] = nr;
            }
            __syncthreads();
        }

        if (tid == 0) {
            const float gold = red[0] + red[1] + red[2] + red[3];
            float a0k[4];
            #pragma unroll
            for (int k = 0; k < 4; ++k) a0k[k] = sf[k] + tr[START * 4 + k];
            const float* P = C + 63 * 16;   // P[k*4+i]
            float aN[4];
            #pragma unroll
            for (int i = 0; i < 4; ++i)
                aN[i] = lse4(a0k[0] + P[0*4+i], a0k[1] + P[1*4+i],
                             a0k[2] + P[2*4+i], a0k[3] + P[3*4+i]);
            const float Z = lse4(aN[0] + tr[0*4+STOP], aN[1] + tr[1*4+STOP],
                                 aN[2] + tr[2*4+STOP], aN[3] + tr[3*4+STOP]);
            ws[WS_ZG + b] = Z - gold;
            out[OUT_ISQA + b] = (float)isqa[b];
            __threadfence();                 // release zg before counter inc
            const int old = atomicAdd((int*)ws + WS_CNT, 1);
            isLast = (old == 63);
        }
        __syncthreads();

        // ---- finisher: last Z-block computes losses + isqa_pred ----
        if (isLast && tid < 64) {
            __threadfence();                 // acquire all blocks' zg/logits
            const float zg = ws[WS_ZG + tid];
            const float l0 = ws[WS_LOGITS + tid * 2 + 0];
            const float l1 = ws[WS_LOGITS + tid * 2 + 1];
            const float m  = fmaxf(l0, l1);
            const float lse = m + __logf(__expf(l0 - m) + __expf(l1 - m));
            const int   y   = isqa[tid];
            const float li  = lse - (y ? l1 : l0);
            float s1 = zg, s2 = li;
            #pragma unroll
            for (int d = 32; d; d >>= 1) {
                s1 += __shfl_xor(s1, d);
                s2 += __shfl_xor(s2, d);
            }
            out[OUT_ISQA_PRED + tid] = (l1 > l0) ? 1.0f : 0.0f;
            if (tid == 0) {
                out[OUT_CRF_LOSS]  = s1 * (1.0f / 64.0f);
                out[OUT_ISQA_LOSS] = s2 * (1.0f / 64.0f);
            }
        }
    } else {
        // ================= V-block: batches 4*(blk-64) .. +3 =================
        const int bv = blk - 64;
        float* sfT = smemf;                                    // 8192 + 16 pad
        unsigned int* bpw = (unsigned int*)(smemf + 8208);     // 4 x 512 words
        {   // stage transposed feats for 4 batches
            float4* d4 = (float4*)sfT;
            const float4* s4 = (const float4*)(ws + WS_FEATST) + bv * 4 * 512;
            #pragma unroll
            for (int n = 0; n < 8; ++n) d4[tid + 256 * n] = s4[tid + 256 * n];
        }
        if (tid < 4) ((float4*)(sfT + 8192))[tid & 3] =
            make_float4(0.f, 0.f, 0.f, 0.f);                   // pad
        __syncthreads();

        const int w    = tid >> 6;
        const int lane = tid & 63;
        const int j    = lane & 3;
        const int b    = bv * 4 + w;
        const int sh8j = 8 * j;

        const float tc0 = trans[0*4+j], tc1 = trans[1*4+j];
        const float tc2 = trans[2*4+j], tc3 = trans[3*4+j];
        const float tSj = trans[START*4+j];
        const float tjs = trans[j*4 + STOP];

        const float4* colT4 = (const float4*)(sfT + w * 2048 + j * 512);
        uint4* bpq = (uint4*)(bpw + w * 512);

        float4 A  = colT4[0];        // t 0..3
        float4 Bq = colT4[1];        // t 4..7
        float4 B2 = colT4[2];        // t 8..11
        float d = A.x + tSj;
        {
            const unsigned int W1 = vstep(d, A.y, tc0, tc1, tc2, tc3, sh8j);
            const unsigned int W2 = vstep(d, A.z, tc0, tc1, tc2, tc3, sh8j);
            const unsigned int W3 = vstep(d, A.w, tc0, tc1, tc2, tc3, sh8j);
            if (lane == 0) bpq[0] = make_uint4(0x03020100u, W1, W2, W3);
        }
        for (int g = 1; g < 128; ++g) {
            const float4 Cq = colT4[g + 2];   // prefetch (pad covers g>=126)
            const unsigned int W0 = vstep(d, Bq.x, tc0, tc1, tc2, tc3, sh8j);
            const unsigned int W1 = vstep(d, Bq.y, tc0, tc1, tc2, tc3, sh8j);
            const unsigned int W2 = vstep(d, Bq.z, tc0, tc1, tc2, tc3, sh8j);
            const unsigned int W3 = vstep(d, Bq.w, tc0, tc1, tc2, tc3, sh8j);
            if (lane == 0) bpq[g] = make_uint4(W0, W1, W2, W3);
            Bq = B2; B2 = Cq;
        }

        // last_tag (first-index-wins argmax over states)
        const float vj = d + tjs;
        const float z0 = dppf<0x00>(vj), z1 = dppf<0x55>(vj);
        const float z2 = dppf<0xAA>(vj), z3 = dppf<0xFF>(vj);
        float m01 = z0; unsigned int i01 = 0;
        if (z1 > m01) { m01 = z1; i01 = 1; }
        float m23 = z2; unsigned int i23 = 2;
        if (z3 > m23) { m23 = z3; i23 = 3; }
        const unsigned int lt = (m23 > m01) ? i23 : i01;

        __syncthreads();

        // backtrack: chunk map composition via v_perm_b32
        const uint4 wv0 = bpq[lane * 2 + 0];   // t = 8L..8L+3
        const uint4 wv1 = bpq[lane * 2 + 1];   // t = 8L+4..8L+7
        unsigned int wk[8] = {wv0.x, wv0.y, wv0.z, wv0.w, wv1.x, wv1.y, wv1.z, wv1.w};
        unsigned int G = wk[7];
        #pragma unroll
        for (int k = 6; k >= 0; --k)
            G = __builtin_amdgcn_perm(0u, wk[k], G);     // f_k ∘ G
        unsigned int Sm = G;
        #pragma unroll
        for (int dd = 1; dd < 64; dd <<= 1) {
            const int srcl = lane + dd;
            const unsigned int oth = __shfl(Sm, (srcl < 64) ? srcl : 63);
            if (srcl < 64) Sm = __builtin_amdgcn_perm(0u, Sm, oth);  // Sm ∘ oth
        }
        unsigned int emap = __shfl(Sm, (lane < 63) ? lane + 1 : 63);
        if (lane == 63) emap = 0x03020100u;
        unsigned int cur = (emap >> (8 * lt)) & 3u;

        float tg[8];
        tg[7] = (float)cur;
        #pragma unroll
        for (int k = 7; k >= 1; --k) {
            cur = (wk[k] >> (8 * cur)) & 3u;
            tg[k - 1] = (float)cur;
        }
        float4* op = (float4*)(out + OUT_CRF_PRED + b * S + lane * 8);
        op[0] = make_float4(tg[0], tg[1], tg[2], tg[3]);
        op[1] = make_float4(tg[4], tg[5], tg[6], tg[7]);
    }
}

// ---------------------------------------------------------------------------
extern "C" void kernel_launch(void* const* d_in, const int* in_sizes, int n_in,
                              void* d_out, int out_size, void* d_ws, size_t ws_size,
                              hipStream_t stream)
{
    const float* emb    = (const float*)d_in[0];
    const int*   ans    = (const int*)d_in[1];
    const int*   isqa   = (const int*)d_in[2];
    const float* fc2_W  = (const float*)d_in[3];
    const float* fc2_b  = (const float*)d_in[4];
    const float* crf_W  = (const float*)d_in[5];
    const float* crf_b  = (const float*)d_in[6];
    const float* trans  = (const float*)d_in[7];
    float* out = (float*)d_out;
    float* ws  = (float*)d_ws;

    feats_kernel<<<512, 256, 0, stream>>>(emb, crf_W, crf_b, ws);
    crf_kernel<<<80, 256, 0, stream>>>(ans, isqa, emb, fc2_W, fc2_b, trans, ws, out);
}

// Round 8
// 198.744 us; speedup vs baseline: 1.5698x; 1.0007x over previous
//
#include <hip/hip_runtime.h>
#include <math.h>

// Problem constants
#define B     64
#define S1    513
#define S     512
#define H     768
#define T     4
#define START 2
#define STOP  3

// d_out layout (floats), reference tuple order:
// (isqa_pred[64,1], crf_pred[64,512], isqa_loss, crf_loss, tags[64,512], IsQA[64,1])
#define OUT_ISQA_PRED 0
#define OUT_CRF_PRED  64
#define OUT_ISQA_LOSS 32832
#define OUT_CRF_LOSS  32833
#define OUT_TAGS      32834
#define OUT_ISQA      65602

// ws layout (floats)
#define WS_FEATS  0                  // [B][S][T]  normal layout
#define WS_LOGITS (B*S*T)            // 131072: [B][2]
#define WS_ZG     (B*S*T + 2*B)      // 131200: [B]
#define WS_CNT    (B*S*T + 3*B)      // 131264: int counter
#define WS_FEATST 131280             // [B][T][S] transposed layout

// feats v3 tiling: 32 rows/block, 4 chunks of 8 complete rows
#define FRB  8      // rows per chunk
#define FNC  4      // chunks per block -> 32 rows/block
#define FRS  193    // LDS row stride in float4 (192 + 1 pad)

// ---------------------------------------------------------------------------
// DPP helpers (quad_perm broadcasts/butterflies within groups of 4 lanes)
// ---------------------------------------------------------------------------
template<int CTRL>
__device__ __forceinline__ float dppf(float x) {
    int v = __builtin_amdgcn_update_dpp(__builtin_bit_cast(int, x),
                                        __builtin_bit_cast(int, x),
                                        CTRL, 0xF, 0xF, false);
    return __builtin_bit_cast(float, v);
}
template<int CTRL>
__device__ __forceinline__ int dppi(int x) {
    return __builtin_amdgcn_update_dpp(x, x, CTRL, 0xF, 0xF, false);
}

__device__ __forceinline__ float lse4(float x0, float x1, float x2, float x3) {
    float m = fmaxf(fmaxf(x0, x1), fmaxf(x2, x3));
    return m + __logf(__expf(x0 - m) + __expf(x1 - m) +
                      __expf(x2 - m) + __expf(x3 - m));
}

// full-wave sum reduction: DPP xor1/xor2 + shfl xor4..32 (result in all lanes)
__device__ __forceinline__ float wred(float a) {
    a += dppf<0xB1>(a); a += dppf<0x4E>(a);
    a += __shfl_xor(a, 4); a += __shfl_xor(a, 8);
    a += __shfl_xor(a, 16); a += __shfl_xor(a, 32);
    return a;
}

__device__ __forceinline__ float dot4(float4 e, float4 w) {
    return e.x * w.x + e.y * w.y + e.z * w.z + e.w * w.w;
}

// ---------------------------------------------------------------------------
// Kernel 1 (v3): feats = emb[:,1:] @ crf_W.T + crf_b — row-chunked streaming.
// 1024 blocks x 256 threads, 32 rows/block in 4 chunks of 8 COMPLETE rows.
// Thread (rb = tid>>5, q = tid&31) owns fixed k-slice {q+32k}, k=0..5, so
// weights live in 24 VGPR float4s (loaded once) — no weight LDS traffic.
// Staging is a linear coalesced tile; double-buffered; 3 blocks/CU overlap
// the per-chunk barrier drains.
// ---------------------------------------------------------------------------
__global__ __launch_bounds__(256, 3) void feats_kernel(
    const float* __restrict__ emb,
    const float* __restrict__ crf_W, const float* __restrict__ crf_b,
    float* __restrict__ ws)
{
    __shared__ float4 buf[2][FRB * FRS];     // ~49.4 KB

    const int tid = threadIdx.x;
    const int blk = blockIdx.x;
    if (blk == 0 && tid == 0) ((int*)ws)[WS_CNT] = 0;

    const int q  = tid & 31;                 // k-slice owner
    const int rb = tid >> 5;                 // row within chunk (0..7)

    // per-thread weights: f4 positions q + 32k, outputs o=0..3 (coalesced)
    const float4* __restrict__ W4 = (const float4*)crf_W;
    float4 wq[4][6];
    #pragma unroll
    for (int o = 0; o < 4; ++o)
        #pragma unroll
        for (int k = 0; k < 6; ++k)
            wq[o][k] = W4[o * 192 + q + 32 * k];
    const float cb0 = crf_b[0], cb1 = crf_b[1], cb2 = crf_b[2], cb3 = crf_b[3];

    const float4* __restrict__ emb4 = (const float4*)emb;
    float* __restrict__ fN = ws + WS_FEATS;
    float* __restrict__ fT = ws + WS_FEATST;
    const int row0 = blk * (FRB * FNC);      // first row of this block

    // ---- staging lambda (manual): chunk c -> buffer sb ----
    // tile = 8 rows x 192 f4 = 1536 f4; thread t covers idx t + 256n, n=0..5
    #define STAGE(c, sb)                                                      \
    {                                                                         \
        _Pragma("unroll")                                                     \
        for (int n = 0; n < 6; ++n) {                                         \
            const int idx = tid + 256 * n;                                    \
            const int r   = idx / 192;                                        \
            const int k4  = idx - r * 192;                                    \
            const int row = row0 + (c) * FRB + r;                             \
            const int bb  = row >> 9;                                         \
            const int ss  = (row & 511) + 1;                                  \
            buf[sb][r * FRS + k4] =                                           \
                emb4[(size_t)(bb * S1 + ss) * (H / 4) + k4];                  \
        }                                                                     \
    }

    STAGE(0, 0);
    __syncthreads();

    int pb = 0;
    for (int c = 0; c < FNC; ++c) {
        if (c + 1 < FNC) STAGE(c + 1, pb ^ 1);

        // compute: thread's strided slice of row rb
        const float4* __restrict__ rowp = &buf[pb][rb * FRS];
        float a0 = 0.f, a1 = 0.f, a2 = 0.f, a3 = 0.f;
        #pragma unroll
        for (int k = 0; k < 6; ++k) {
            const float4 e = rowp[q + 32 * k];
            a0 += dot4(e, wq[0][k]);
            a1 += dot4(e, wq[1][k]);
            a2 += dot4(e, wq[2][k]);
            a3 += dot4(e, wq[3][k]);
        }
        // reduce across the 32 q-lanes (stays within each 32-lane half)
        #pragma unroll
        for (int d = 1; d <= 16; d <<= 1) {
            a0 += __shfl_xor(a0, d);
            a1 += __shfl_xor(a1, d);
            a2 += __shfl_xor(a2, d);
            a3 += __shfl_xor(a3, d);
        }
        if (q == 0) {
            const int row = row0 + c * FRB + rb;
            const int bb  = row >> 9;
            const int ss  = (row & 511) + 1;
            const float v0 = a0 + cb0, v1 = a1 + cb1;
            const float v2 = a2 + cb2, v3 = a3 + cb3;
            ((float4*)fN)[bb * S + (ss - 1)] = make_float4(v0, v1, v2, v3);
            const int tb = bb * 4 * S + (ss - 1);
            fT[tb + 0 * S] = v0;
            fT[tb + 1 * S] = v1;
            fT[tb + 2 * S] = v2;
            fT[tb + 3 * S] = v3;
        }
        __syncthreads();
        pb ^= 1;
    }
    #undef STAGE
}

// ---------------------------------------------------------------------------
// Viterbi step: bit-exact value path (max of exact sums + add), first-index
// argmax; returns quad-packed map word (byte j = argmax for state j).
// ---------------------------------------------------------------------------
__device__ __forceinline__ unsigned int vstep(
    float& d, float fv,
    float tc0, float tc1, float tc2, float tc3, int sh8j)
{
    const float d0 = dppf<0x00>(d), d1 = dppf<0x55>(d);
    const float d2 = dppf<0xAA>(d), d3 = dppf<0xFF>(d);
    const float y0 = d0 + tc0, y1 = d1 + tc1;
    const float y2 = d2 + tc2, y3 = d3 + tc3;
    const float m01 = fmaxf(y0, y1), m23 = fmaxf(y2, y3);
    const int   i01 = (y1 > y0) ? 1 : 0;
    const int   i23 = (y3 > y2) ? 3 : 2;
    const int   bi  = (m23 > m01) ? i23 : i01;
    d = fmaxf(m01, m23) + fv;
    unsigned int mb = (unsigned int)bi << sh8j;      // byte slot j
    unsigned int t1 = mb | (unsigned int)dppi<0xB1>((int)mb);
    return t1 | (unsigned int)dppi<0x4E>((int)t1);
}

// ---------------------------------------------------------------------------
// Kernel 2: grid 80.
// Blocks 0..63 (Z): per-batch log-partition (chunked log-semiring scan), gold
//   score, tags echo, IsQA echo, fc2 logits; last block computes final losses.
// Blocks 64..79 (V): 4 batches each; bit-exact sequential Viterbi with
//   transposed-LDS b128 feats prefetch + packed backpointers; map-composition
//   backtrack.
// ---------------------------------------------------------------------------
__global__ __launch_bounds__(256) void crf_kernel(
    const int* __restrict__ ans, const int* __restrict__ isqa,
    const float* __restrict__ emb,
    const float* __restrict__ fc2_W, const float* __restrict__ fc2_b,
    const float* __restrict__ trans,
    float* __restrict__ ws, float* __restrict__ out)
{
    __shared__ float smemf[10784];   // V: sfT 8192 + pad 16 + bpw 2048 words
    __shared__ int isLast;
    const int tid = threadIdx.x;
    const int blk = blockIdx.x;

    if (blk < 64) {
        // ================= Z-block: batch b =================
        const int b = blk;
        float* sf  = smemf;            // 2048 floats
        float* C   = smemf + 2048;     // 64 chunk matrices x 16
        float* red = smemf + 3072;     // 4 floats

        float tr[16];
        #pragma unroll
        for (int i = 0; i < 16; ++i) tr[i] = trans[i];

        {   // stage feats[b] (normal layout)
            float4* sf4 = (float4*)sf;
            const float4* src4 = (const float4*)(ws + WS_FEATS) + b * 512;
            sf4[tid] = src4[tid];
            sf4[tid + 256] = src4[tid + 256];
        }

        // ---- fc2 logits for this batch (waves 0,1), independent of LDS ----
        if (tid < 128) {
            const int wv   = tid >> 6;       // 0 or 1
            const int lane = tid & 63;
            const float4* e4 = (const float4*)emb + (size_t)b * S1 * (H / 4);
            const float4* w4 = (const float4*)fc2_W + wv * 192;
            float acc = 0.f;
            #pragma unroll
            for (int k = 0; k < 3; ++k) {
                const float4 e = e4[lane + 64 * k];
                const float4 w = w4[lane + 64 * k];
                acc += dot4(e, w);
            }
            acc = wred(acc);
            if (lane == 0) {
                ws[WS_LOGITS + 2 * b + wv] = acc + fc2_b[wv];
                __threadfence();             // release this store device-wide
            }
        }
        __syncthreads();

        // ---- gold score + tags echo ----
        float g = 0.f;
        #pragma unroll
        for (int u = 0; u < 2; ++u) {
            const int t   = 2 * tid + u;
            const int tag = ans[b * S1 + 1 + t];
            out[OUT_TAGS + b * S + t] = (float)tag;
            g += sf[t * 4 + tag];
            g += (t == 0) ? tr[START * 4 + tag] : tr[ans[b * S1 + t] * 4 + tag];
            if (t == S - 1) g += tr[tag * 4 + STOP];
        }
        #pragma unroll
        for (int m = 32; m; m >>= 1) g += __shfl_xor(g, m);
        if ((tid & 63) == 0) red[tid >> 6] = g;

        // ---- Phase A: chunk matrices, thread (c,jr) owns row jr of chunk c ----
        const int c  = tid >> 2;
        const int jr = tid & 3;
        const int t0 = c ? 8 * c : 1;
        float rl[4];
        #pragma unroll
        for (int i = 0; i < 4; ++i) rl[i] = tr[jr * 4 + i] + sf[t0 * 4 + i];
        for (int t = t0 + 1; t <= 8 * c + 7; ++t) {
            const float f0 = sf[t*4+0], f1 = sf[t*4+1], f2 = sf[t*4+2], f3 = sf[t*4+3];
            float nr[4];
            #pragma unroll
            for (int i = 0; i < 4; ++i)
                nr[i] = lse4(rl[0] + tr[0*4+i], rl[1] + tr[1*4+i],
                             rl[2] + tr[2*4+i], rl[3] + tr[3*4+i]);
            rl[0] = nr[0] + f0; rl[1] = nr[1] + f1;
            rl[2] = nr[2] + f2; rl[3] = nr[3] + f3;
        }
        ((float4*)C)[c * 4 + jr] = make_float4(rl[0], rl[1], rl[2], rl[3]);
        __syncthreads();

        // ---- Hillis-Steele inclusive scan over 64 chunk matrices ----
        for (int d = 1; d <= 32; d <<= 1) {
            const int cs = (c >= d) ? (c - d) : c;
            float4 ar = ((float4*)C)[cs * 4 + jr];
            float4 b0 = ((float4*)C)[c * 4 + 0];
            float4 b1 = ((float4*)C)[c * 4 + 1];
            float4 b2 = ((float4*)C)[c * 4 + 2];
            float4 b3 = ((float4*)C)[c * 4 + 3];
            __syncthreads();
            if (c >= d) {
                float4 nr;
                nr.x = lse4(ar.x + b0.x, ar.y + b1.x, ar.z + b2.x, ar.w + b3.x);
                nr.y = lse4(ar.x + b0.y, ar.y + b1.y, ar.z + b2.y, ar.w + b3.y);
                nr.z = lse4(ar.x + b0.z, ar.y + b1.z, ar.z + b2.z, ar.w + b3.z);
                nr.w = lse4(ar.x + b0.w, ar.y + b1.w, ar.z + b2.w, ar.w + b3.w);
                ((float4*)C)[c * 4 + jr] = nr;
            }
            __syncthreads();
        }

        if (tid == 0) {
            const float gold = red[0] + red[1] + red[2] + red[3];
            float a0k[4];
            #pragma unroll
            for (int k = 0; k < 4; ++k) a0k[k] = sf[k] + tr[START * 4 + k];
            const float* P = C + 63 * 16;   // P[k*4+i]
            float aN[4];
            #pragma unroll
            for (int i = 0; i < 4; ++i)
                aN[i] = lse4(a0k[0] + P[0*4+i], a0k[1] + P[1*4+i],
                             a0k[2] + P[2*4+i], a0k[3] + P[3*4+i]);
            const float Z = lse4(aN[0] + tr[0*4+STOP], aN[1] + tr[1*4+STOP],
                                 aN[2] + tr[2*4+STOP], aN[3] + tr[3*4+STOP]);
            ws[WS_ZG + b] = Z - gold;
            out[OUT_ISQA + b] = (float)isqa[b];
            __threadfence();                 // release zg before counter inc
            const int old = atomicAdd((int*)ws + WS_CNT, 1);
            isLast = (old == 63);
        }
        __syncthreads();

        // ---- finisher: last Z-block computes losses + isqa_pred ----
        if (isLast && tid < 64) {
            __threadfence();                 // acquire all blocks' zg/logits
            const float zg = ws[WS_ZG + tid];
            const float l0 = ws[WS_LOGITS + tid * 2 + 0];
            const float l1 = ws[WS_LOGITS + tid * 2 + 1];
            const float m  = fmaxf(l0, l1);
            const float lse = m + __logf(__expf(l0 - m) + __expf(l1 - m));
            const int   y   = isqa[tid];
            const float li  = lse - (y ? l1 : l0);
            float s1 = zg, s2 = li;
            #pragma unroll
            for (int d = 32; d; d >>= 1) {
                s1 += __shfl_xor(s1, d);
                s2 += __shfl_xor(s2, d);
            }
            out[OUT_ISQA_PRED + tid] = (l1 > l0) ? 1.0f : 0.0f;
            if (tid == 0) {
                out[OUT_CRF_LOSS]  = s1 * (1.0f / 64.0f);
                out[OUT_ISQA_LOSS] = s2 * (1.0f / 64.0f);
            }
        }
    } else {
        // ================= V-block: batches 4*(blk-64) .. +3 =================
        const int bv = blk - 64;
        float* sfT = smemf;                                    // 8192 + 16 pad
        unsigned int* bpw = (unsigned int*)(smemf + 8208);     // 4 x 512 words
        {   // stage transposed feats for 4 batches
            float4* d4 = (float4*)sfT;
            const float4* s4 = (const float4*)(ws + WS_FEATST) + bv * 4 * 512;
            #pragma unroll
            for (int n = 0; n < 8; ++n) d4[tid + 256 * n] = s4[tid + 256 * n];
        }
        if (tid < 4) ((float4*)(sfT + 8192))[tid & 3] =
            make_float4(0.f, 0.f, 0.f, 0.f);                   // pad
        __syncthreads();

        const int w    = tid >> 6;
        const int lane = tid & 63;
        const int j    = lane & 3;
        const int b    = bv * 4 + w;
        const int sh8j = 8 * j;

        const float tc0 = trans[0*4+j], tc1 = trans[1*4+j];
        const float tc2 = trans[2*4+j], tc3 = trans[3*4+j];
        const float tSj = trans[START*4+j];
        const float tjs = trans[j*4 + STOP];

        const float4* colT4 = (const float4*)(sfT + w * 2048 + j * 512);
        uint4* bpq = (uint4*)(bpw + w * 512);

        float4 A  = colT4[0];        // t 0..3
        float4 Bq = colT4[1];        // t 4..7
        float4 B2 = colT4[2];        // t 8..11
        float d = A.x + tSj;
        {
            const unsigned int W1 = vstep(d, A.y, tc0, tc1, tc2, tc3, sh8j);
            const unsigned int W2 = vstep(d, A.z, tc0, tc1, tc2, tc3, sh8j);
            const unsigned int W3 = vstep(d, A.w, tc0, tc1, tc2, tc3, sh8j);
            if (lane == 0) bpq[0] = make_uint4(0x03020100u, W1, W2, W3);
        }
        for (int g = 1; g < 128; ++g) {
            const float4 Cq = colT4[g + 2];   // prefetch (pad covers g>=126)
            const unsigned int W0 = vstep(d, Bq.x, tc0, tc1, tc2, tc3, sh8j);
            const unsigned int W1 = vstep(d, Bq.y, tc0, tc1, tc2, tc3, sh8j);
            const unsigned int W2 = vstep(d, Bq.z, tc0, tc1, tc2, tc3, sh8j);
            const unsigned int W3 = vstep(d, Bq.w, tc0, tc1, tc2, tc3, sh8j);
            if (lane == 0) bpq[g] = make_uint4(W0, W1, W2, W3);
            Bq = B2; B2 = Cq;
        }

        // last_tag (first-index-wins argmax over states)
        const float vj = d + tjs;
        const float z0 = dppf<0x00>(vj), z1 = dppf<0x55>(vj);
        const float z2 = dppf<0xAA>(vj), z3 = dppf<0xFF>(vj);
        float m01 = z0; unsigned int i01 = 0;
        if (z1 > m01) { m01 = z1; i01 = 1; }
        float m23 = z2; unsigned int i23 = 2;
        if (z3 > m23) { m23 = z3; i23 = 3; }
        const unsigned int lt = (m23 > m01) ? i23 : i01;

        __syncthreads();

        // backtrack: chunk map composition via v_perm_b32
        const uint4 wv0 = bpq[lane * 2 + 0];   // t = 8L..8L+3
        const uint4 wv1 = bpq[lane * 2 + 1];   // t = 8L+4..8L+7
        unsigned int wk[8] = {wv0.x, wv0.y, wv0.z, wv0.w, wv1.x, wv1.y, wv1.z, wv1.w};
        unsigned int G = wk[7];
        #pragma unroll
        for (int k = 6; k >= 0; --k)
            G = __builtin_amdgcn_perm(0u, wk[k], G);     // f_k ∘ G
        unsigned int Sm = G;
        #pragma unroll
        for (int dd = 1; dd < 64; dd <<= 1) {
            const int srcl = lane + dd;
            const unsigned int oth = __shfl(Sm, (srcl < 64) ? srcl : 63);
            if (srcl < 64) Sm = __builtin_amdgcn_perm(0u, Sm, oth);  // Sm ∘ oth
        }
        unsigned int emap = __shfl(Sm, (lane < 63) ? lane + 1 : 63);
        if (lane == 63) emap = 0x03020100u;
        unsigned int cur = (emap >> (8 * lt)) & 3u;

        float tg[8];
        tg[7] = (float)cur;
        #pragma unroll
        for (int k = 7; k >= 1; --k) {
            cur = (wk[k] >> (8 * cur)) & 3u;
            tg[k - 1] = (float)cur;
        }
        float4* op = (float4*)(out + OUT_CRF_PRED + b * S + lane * 8);
        op[0] = make_float4(tg[0], tg[1], tg[2], tg[3]);
        op[1] = make_float4(tg[4], tg[5], tg[6], tg[7]);
    }
}

// ---------------------------------------------------------------------------
extern "C" void kernel_launch(void* const* d_in, const int* in_sizes, int n_in,
                              void* d_out, int out_size, void* d_ws, size_t ws_size,
                              hipStream_t stream)
{
    const float* emb    = (const float*)d_in[0];
    const int*   ans    = (const int*)d_in[1];
    const int*   isqa   = (const int*)d_in[2];
    const float* fc2_W  = (const float*)d_in[3];
    const float* fc2_b  = (const float*)d_in[4];
    const float* crf_W  = (const float*)d_in[5];
    const float* crf_b  = (const float*)d_in[6];
    const float* trans  = (const float*)d_in[7];
    float* out = (float*)d_out;
    float* ws  = (float*)d_ws;

    feats_kernel<<<1024, 256, 0, stream>>>(emb, crf_W, crf_b, ws);
    crf_kernel<<<80, 256, 0, stream>>>(ans, isqa, emb, fc2_W, fc2_b, trans, ws, out);
}

// Round 9
// 194.417 us; speedup vs baseline: 1.6047x; 1.0223x over previous
//
#include <hip/hip_runtime.h>
#include <math.h>

// Problem constants
#define B     64
#define S1    513
#define S     512
#define H     768
#define T     4
#define START 2
#define STOP  3

// d_out layout (floats), reference tuple order:
// (isqa_pred[64,1], crf_pred[64,512], isqa_loss, crf_loss, tags[64,512], IsQA[64,1])
#define OUT_ISQA_PRED 0
#define OUT_CRF_PRED  64
#define OUT_ISQA_LOSS 32832
#define OUT_CRF_LOSS  32833
#define OUT_TAGS      32834
#define OUT_ISQA      65602

// ws layout (floats)
#define WS_FEATS  0                  // [B][S][T]  normal layout
#define WS_LOGITS (B*S*T)            // 131072: [B][2]
#define WS_ZG     (B*S*T + 2*B)      // 131200: [B]
#define WS_CNT    (B*S*T + 3*B)      // 131264: int counter
#define WS_FEATST 131280             // [B][T][S] transposed layout

// feats v3 tiling: 32 rows/block, 4 chunks of 8 complete rows
#define FRB  8      // rows per chunk
#define FNC  4      // chunks per block -> 32 rows/block
#define FRS  193    // LDS row stride in float4 (192 + 1 pad)

// ---------------------------------------------------------------------------
// DPP helpers (quad_perm broadcasts/butterflies within groups of 4 lanes)
// ---------------------------------------------------------------------------
template<int CTRL>
__device__ __forceinline__ float dppf(float x) {
    int v = __builtin_amdgcn_update_dpp(__builtin_bit_cast(int, x),
                                        __builtin_bit_cast(int, x),
                                        CTRL, 0xF, 0xF, false);
    return __builtin_bit_cast(float, v);
}
template<int CTRL>
__device__ __forceinline__ int dppi(int x) {
    return __builtin_amdgcn_update_dpp(x, x, CTRL, 0xF, 0xF, false);
}

__device__ __forceinline__ float lse4(float x0, float x1, float x2, float x3) {
    float m = fmaxf(fmaxf(x0, x1), fmaxf(x2, x3));
    return m + __logf(__expf(x0 - m) + __expf(x1 - m) +
                      __expf(x2 - m) + __expf(x3 - m));
}

// full-wave sum reduction: DPP xor1/xor2 + shfl xor4..32 (result in all lanes)
__device__ __forceinline__ float wred(float a) {
    a += dppf<0xB1>(a); a += dppf<0x4E>(a);
    a += __shfl_xor(a, 4); a += __shfl_xor(a, 8);
    a += __shfl_xor(a, 16); a += __shfl_xor(a, 32);
    return a;
}

__device__ __forceinline__ float dot4(float4 e, float4 w) {
    return e.x * w.x + e.y * w.y + e.z * w.z + e.w * w.w;
}

// non-temporal float4 load (streaming-once read; avoid L2/L3 allocation)
__device__ __forceinline__ float4 ntload4(const float4* p) {
    float4 r;
    r.x = __builtin_nontemporal_load(&p->x);
    r.y = __builtin_nontemporal_load(&p->y);
    r.z = __builtin_nontemporal_load(&p->z);
    r.w = __builtin_nontemporal_load(&p->w);
    return r;
}

// ---------------------------------------------------------------------------
// Kernel 1 (v3+NT): feats = emb[:,1:] @ crf_W.T + crf_b — row-chunked stream.
// Identical to round-8 kernel EXCEPT emb reads are non-temporal.
// ---------------------------------------------------------------------------
__global__ __launch_bounds__(256, 3) void feats_kernel(
    const float* __restrict__ emb,
    const float* __restrict__ crf_W, const float* __restrict__ crf_b,
    float* __restrict__ ws)
{
    __shared__ float4 buf[2][FRB * FRS];     // ~49.4 KB

    const int tid = threadIdx.x;
    const int blk = blockIdx.x;
    if (blk == 0 && tid == 0) ((int*)ws)[WS_CNT] = 0;

    const int q  = tid & 31;                 // k-slice owner
    const int rb = tid >> 5;                 // row within chunk (0..7)

    // per-thread weights: f4 positions q + 32k, outputs o=0..3 (coalesced)
    const float4* __restrict__ W4 = (const float4*)crf_W;
    float4 wq[4][6];
    #pragma unroll
    for (int o = 0; o < 4; ++o)
        #pragma unroll
        for (int k = 0; k < 6; ++k)
            wq[o][k] = W4[o * 192 + q + 32 * k];
    const float cb0 = crf_b[0], cb1 = crf_b[1], cb2 = crf_b[2], cb3 = crf_b[3];

    const float4* __restrict__ emb4 = (const float4*)emb;
    float* __restrict__ fN = ws + WS_FEATS;
    float* __restrict__ fT = ws + WS_FEATST;
    const int row0 = blk * (FRB * FNC);      // first row of this block

    // ---- staging: chunk c -> buffer sb (non-temporal reads) ----
    #define STAGE(c, sb)                                                      \
    {                                                                         \
        _Pragma("unroll")                                                     \
        for (int n = 0; n < 6; ++n) {                                         \
            const int idx = tid + 256 * n;                                    \
            const int r   = idx / 192;                                        \
            const int k4  = idx - r * 192;                                    \
            const int row = row0 + (c) * FRB + r;                             \
            const int bb  = row >> 9;                                         \
            const int ss  = (row & 511) + 1;                                  \
            buf[sb][r * FRS + k4] =                                           \
                ntload4(&emb4[(size_t)(bb * S1 + ss) * (H / 4) + k4]);        \
        }                                                                     \
    }

    STAGE(0, 0);
    __syncthreads();

    int pb = 0;
    for (int c = 0; c < FNC; ++c) {
        if (c + 1 < FNC) STAGE(c + 1, pb ^ 1);

        // compute: thread's strided slice of row rb
        const float4* __restrict__ rowp = &buf[pb][rb * FRS];
        float a0 = 0.f, a1 = 0.f, a2 = 0.f, a3 = 0.f;
        #pragma unroll
        for (int k = 0; k < 6; ++k) {
            const float4 e = rowp[q + 32 * k];
            a0 += dot4(e, wq[0][k]);
            a1 += dot4(e, wq[1][k]);
            a2 += dot4(e, wq[2][k]);
            a3 += dot4(e, wq[3][k]);
        }
        // reduce across the 32 q-lanes (stays within each 32-lane half)
        #pragma unroll
        for (int d = 1; d <= 16; d <<= 1) {
            a0 += __shfl_xor(a0, d);
            a1 += __shfl_xor(a1, d);
            a2 += __shfl_xor(a2, d);
            a3 += __shfl_xor(a3, d);
        }
        if (q == 0) {
            const int row = row0 + c * FRB + rb;
            const int bb  = row >> 9;
            const int ss  = (row & 511) + 1;
            const float v0 = a0 + cb0, v1 = a1 + cb1;
            const float v2 = a2 + cb2, v3 = a3 + cb3;
            ((float4*)fN)[bb * S + (ss - 1)] = make_float4(v0, v1, v2, v3);
            const int tb = bb * 4 * S + (ss - 1);
            fT[tb + 0 * S] = v0;
            fT[tb + 1 * S] = v1;
            fT[tb + 2 * S] = v2;
            fT[tb + 3 * S] = v3;
        }
        __syncthreads();
        pb ^= 1;
    }
    #undef STAGE
}

// ---------------------------------------------------------------------------
// Viterbi step: bit-exact value path (max of exact sums + add), first-index
// argmax; returns quad-packed map word (byte j = argmax for state j).
// ---------------------------------------------------------------------------
__device__ __forceinline__ unsigned int vstep(
    float& d, float fv,
    float tc0, float tc1, float tc2, float tc3, int sh8j)
{
    const float d0 = dppf<0x00>(d), d1 = dppf<0x55>(d);
    const float d2 = dppf<0xAA>(d), d3 = dppf<0xFF>(d);
    const float y0 = d0 + tc0, y1 = d1 + tc1;
    const float y2 = d2 + tc2, y3 = d3 + tc3;
    const float m01 = fmaxf(y0, y1), m23 = fmaxf(y2, y3);
    const int   i01 = (y1 > y0) ? 1 : 0;
    const int   i23 = (y3 > y2) ? 3 : 2;
    const int   bi  = (m23 > m01) ? i23 : i01;
    d = fmaxf(m01, m23) + fv;
    unsigned int mb = (unsigned int)bi << sh8j;      // byte slot j
    unsigned int t1 = mb | (unsigned int)dppi<0xB1>((int)mb);
    return t1 | (unsigned int)dppi<0x4E>((int)t1);
}

// ---------------------------------------------------------------------------
// Kernel 2: grid 80.  (byte-identical to round 4/7/8 — verified absmax 0.0)
// ---------------------------------------------------------------------------
__global__ __launch_bounds__(256) void crf_kernel(
    const int* __restrict__ ans, const int* __restrict__ isqa,
    const float* __restrict__ emb,
    const float* __restrict__ fc2_W, const float* __restrict__ fc2_b,
    const float* __restrict__ trans,
    float* __restrict__ ws, float* __restrict__ out)
{
    __shared__ float smemf[10784];   // V: sfT 8192 + pad 16 + bpw 2048 words
    __shared__ int isLast;
    const int tid = threadIdx.x;
    const int blk = blockIdx.x;

    if (blk < 64) {
        // ================= Z-block: batch b =================
        const int b = blk;
        float* sf  = smemf;            // 2048 floats
        float* C   = smemf + 2048;     // 64 chunk matrices x 16
        float* red = smemf + 3072;     // 4 floats

        float tr[16];
        #pragma unroll
        for (int i = 0; i < 16; ++i) tr[i] = trans[i];

        {   // stage feats[b] (normal layout)
            float4* sf4 = (float4*)sf;
            const float4* src4 = (const float4*)(ws + WS_FEATS) + b * 512;
            sf4[tid] = src4[tid];
            sf4[tid + 256] = src4[tid + 256];
        }

        // ---- fc2 logits for this batch (waves 0,1), independent of LDS ----
        if (tid < 128) {
            const int wv   = tid >> 6;       // 0 or 1
            const int lane = tid & 63;
            const float4* e4 = (const float4*)emb + (size_t)b * S1 * (H / 4);
            const float4* w4 = (const float4*)fc2_W + wv * 192;
            float acc = 0.f;
            #pragma unroll
            for (int k = 0; k < 3; ++k) {
                const float4 e = e4[lane + 64 * k];
                const float4 w = w4[lane + 64 * k];
                acc += dot4(e, w);
            }
            acc = wred(acc);
            if (lane == 0) {
                ws[WS_LOGITS + 2 * b + wv] = acc + fc2_b[wv];
                __threadfence();             // release this store device-wide
            }
        }
        __syncthreads();

        // ---- gold score + tags echo ----
        float g = 0.f;
        #pragma unroll
        for (int u = 0; u < 2; ++u) {
            const int t   = 2 * tid + u;
            const int tag = ans[b * S1 + 1 + t];
            out[OUT_TAGS + b * S + t] = (float)tag;
            g += sf[t * 4 + tag];
            g += (t == 0) ? tr[START * 4 + tag] : tr[ans[b * S1 + t] * 4 + tag];
            if (t == S - 1) g += tr[tag * 4 + STOP];
        }
        #pragma unroll
        for (int m = 32; m; m >>= 1) g += __shfl_xor(g, m);
        if ((tid & 63) == 0) red[tid >> 6] = g;

        // ---- Phase A: chunk matrices, thread (c,jr) owns row jr of chunk c ----
        const int c  = tid >> 2;
        const int jr = tid & 3;
        const int t0 = c ? 8 * c : 1;
        float rl[4];
        #pragma unroll
        for (int i = 0; i < 4; ++i) rl[i] = tr[jr * 4 + i] + sf[t0 * 4 + i];
        for (int t = t0 + 1; t <= 8 * c + 7; ++t) {
            const float f0 = sf[t*4+0], f1 = sf[t*4+1], f2 = sf[t*4+2], f3 = sf[t*4+3];
            float nr[4];
            #pragma unroll
            for (int i = 0; i < 4; ++i)
                nr[i] = lse4(rl[0] + tr[0*4+i], rl[1] + tr[1*4+i],
                             rl[2] + tr[2*4+i], rl[3] + tr[3*4+i]);
            rl[0] = nr[0] + f0; rl[1] = nr[1] + f1;
            rl[2] = nr[2] + f2; rl[3] = nr[3] + f3;
        }
        ((float4*)C)[c * 4 + jr] = make_float4(rl[0], rl[1], rl[2], rl[3]);
        __syncthreads();

        // ---- Hillis-Steele inclusive scan over 64 chunk matrices ----
        for (int d = 1; d <= 32; d <<= 1) {
            const int cs = (c >= d) ? (c - d) : c;
            float4 ar = ((float4*)C)[cs * 4 + jr];
            float4 b0 = ((float4*)C)[c * 4 + 0];
            float4 b1 = ((float4*)C)[c * 4 + 1];
            float4 b2 = ((float4*)C)[c * 4 + 2];
            float4 b3 = ((float4*)C)[c * 4 + 3];
            __syncthreads();
            if (c >= d) {
                float4 nr;
                nr.x = lse4(ar.x + b0.x, ar.y + b1.x, ar.z + b2.x, ar.w + b3.x);
                nr.y = lse4(ar.x + b0.y, ar.y + b1.y, ar.z + b2.y, ar.w + b3.y);
                nr.z = lse4(ar.x + b0.z, ar.y + b1.z, ar.z + b2.z, ar.w + b3.z);
                nr.w = lse4(ar.x + b0.w, ar.y + b1.w, ar.z + b2.w, ar.w + b3.w);
                ((float4*)C)[c * 4 + jr] = nr;
            }
            __syncthreads();
        }

        if (tid == 0) {
            const float gold = red[0] + red[1] + red[2] + red[3];
            float a0k[4];
            #pragma unroll
            for (int k = 0; k < 4; ++k) a0k[k] = sf[k] + tr[START * 4 + k];
            const float* P = C + 63 * 16;   // P[k*4+i]
            float aN[4];
            #pragma unroll
            for (int i = 0; i < 4; ++i)
                aN[i] = lse4(a0k[0] + P[0*4+i], a0k[1] + P[1*4+i],
                             a0k[2] + P[2*4+i], a0k[3] + P[3*4+i]);
            const float Z = lse4(aN[0] + tr[0*4+STOP], aN[1] + tr[1*4+STOP],
                                 aN[2] + tr[2*4+STOP], aN[3] + tr[3*4+STOP]);
            ws[WS_ZG + b] = Z - gold;
            out[OUT_ISQA + b] = (float)isqa[b];
            __threadfence();                 // release zg before counter inc
            const int old = atomicAdd((int*)ws + WS_CNT, 1);
            isLast = (old == 63);
        }
        __syncthreads();

        // ---- finisher: last Z-block computes losses + isqa_pred ----
        if (isLast && tid < 64) {
            __threadfence();                 // acquire all blocks' zg/logits
            const float zg = ws[WS_ZG + tid];
            const float l0 = ws[WS_LOGITS + tid * 2 + 0];
            const float l1 = ws[WS_LOGITS + tid * 2 + 1];
            const float m  = fmaxf(l0, l1);
            const float lse = m + __logf(__expf(l0 - m) + __expf(l1 - m));
            const int   y   = isqa[tid];
            const float li  = lse - (y ? l1 : l0);
            float s1 = zg, s2 = li;
            #pragma unroll
            for (int d = 32; d; d >>= 1) {
                s1 += __shfl_xor(s1, d);
                s2 += __shfl_xor(s2, d);
            }
            out[OUT_ISQA_PRED + tid] = (l1 > l0) ? 1.0f : 0.0f;
            if (tid == 0) {
                out[OUT_CRF_LOSS]  = s1 * (1.0f / 64.0f);
                out[OUT_ISQA_LOSS] = s2 * (1.0f / 64.0f);
            }
        }
    } else {
        // ================= V-block: batches 4*(blk-64) .. +3 =================
        const int bv = blk - 64;
        float* sfT = smemf;                                    // 8192 + 16 pad
        unsigned int* bpw = (unsigned int*)(smemf + 8208);     // 4 x 512 words
        {   // stage transposed feats for 4 batches
            float4* d4 = (float4*)sfT;
            const float4* s4 = (const float4*)(ws + WS_FEATST) + bv * 4 * 512;
            #pragma unroll
            for (int n = 0; n < 8; ++n) d4[tid + 256 * n] = s4[tid + 256 * n];
        }
        if (tid < 4) ((float4*)(sfT + 8192))[tid & 3] =
            make_float4(0.f, 0.f, 0.f, 0.f);                   // pad
        __syncthreads();

        const int w    = tid >> 6;
        const int lane = tid & 63;
        const int j    = lane & 3;
        const int b    = bv * 4 + w;
        const int sh8j = 8 * j;

        const float tc0 = trans[0*4+j], tc1 = trans[1*4+j];
        const float tc2 = trans[2*4+j], tc3 = trans[3*4+j];
        const float tSj = trans[START*4+j];
        const float tjs = trans[j*4 + STOP];

        const float4* colT4 = (const float4*)(sfT + w * 2048 + j * 512);
        uint4* bpq = (uint4*)(bpw + w * 512);

        float4 A  = colT4[0];        // t 0..3
        float4 Bq = colT4[1];        // t 4..7
        float4 B2 = colT4[2];        // t 8..11
        float d = A.x + tSj;
        {
            const unsigned int W1 = vstep(d, A.y, tc0, tc1, tc2, tc3, sh8j);
            const unsigned int W2 = vstep(d, A.z, tc0, tc1, tc2, tc3, sh8j);
            const unsigned int W3 = vstep(d, A.w, tc0, tc1, tc2, tc3, sh8j);
            if (lane == 0) bpq[0] = make_uint4(0x03020100u, W1, W2, W3);
        }
        for (int g = 1; g < 128; ++g) {
            const float4 Cq = colT4[g + 2];   // prefetch (pad covers g>=126)
            const unsigned int W0 = vstep(d, Bq.x, tc0, tc1, tc2, tc3, sh8j);
            const unsigned int W1 = vstep(d, Bq.y, tc0, tc1, tc2, tc3, sh8j);
            const unsigned int W2 = vstep(d, Bq.z, tc0, tc1, tc2, tc3, sh8j);
            const unsigned int W3 = vstep(d, Bq.w, tc0, tc1, tc2, tc3, sh8j);
            if (lane == 0) bpq[g] = make_uint4(W0, W1, W2, W3);
            Bq = B2; B2 = Cq;
        }

        // last_tag (first-index-wins argmax over states)
        const float vj = d + tjs;
        const float z0 = dppf<0x00>(vj), z1 = dppf<0x55>(vj);
        const float z2 = dppf<0xAA>(vj), z3 = dppf<0xFF>(vj);
        float m01 = z0; unsigned int i01 = 0;
        if (z1 > m01) { m01 = z1; i01 = 1; }
        float m23 = z2; unsigned int i23 = 2;
        if (z3 > m23) { m23 = z3; i23 = 3; }
        const unsigned int lt = (m23 > m01) ? i23 : i01;

        __syncthreads();

        // backtrack: chunk map composition via v_perm_b32
        const uint4 wv0 = bpq[lane * 2 + 0];   // t = 8L..8L+3
        const uint4 wv1 = bpq[lane * 2 + 1];   // t = 8L+4..8L+7
        unsigned int wk[8] = {wv0.x, wv0.y, wv0.z, wv0.w, wv1.x, wv1.y, wv1.z, wv1.w};
        unsigned int G = wk[7];
        #pragma unroll
        for (int k = 6; k >= 0; --k)
            G = __builtin_amdgcn_perm(0u, wk[k], G);     // f_k ∘ G
        unsigned int Sm = G;
        #pragma unroll
        for (int dd = 1; dd < 64; dd <<= 1) {
            const int srcl = lane + dd;
            const unsigned int oth = __shfl(Sm, (srcl < 64) ? srcl : 63);
            if (srcl < 64) Sm = __builtin_amdgcn_perm(0u, Sm, oth);  // Sm ∘ oth
        }
        unsigned int emap = __shfl(Sm, (lane < 63) ? lane + 1 : 63);
        if (lane == 63) emap = 0x03020100u;
        unsigned int cur = (emap >> (8 * lt)) & 3u;

        float tg[8];
        tg[7] = (float)cur;
        #pragma unroll
        for (int k = 7; k >= 1; --k) {
            cur = (wk[k] >> (8 * cur)) & 3u;
            tg[k - 1] = (float)cur;
        }
        float4* op = (float4*)(out + OUT_CRF_PRED + b * S + lane * 8);
        op[0] = make_float4(tg[0], tg[1], tg[2], tg[3]);
        op[1] = make_float4(tg[4], tg[5], tg[6], tg[7]);
    }
}

// ---------------------------------------------------------------------------
extern "C" void kernel_launch(void* const* d_in, const int* in_sizes, int n_in,
                              void* d_out, int out_size, void* d_ws, size_t ws_size,
                              hipStream_t stream)
{
    const float* emb    = (const float*)d_in[0];
    const int*   ans    = (const int*)d_in[1];
    const int*   isqa   = (const int*)d_in[2];
    const float* fc2_W  = (const float*)d_in[3];
    const float* fc2_b  = (const float*)d_in[4];
    const float* crf_W  = (const float*)d_in[5];
    const float* crf_b  = (const float*)d_in[6];
    const float* trans  = (const float*)d_in[7];
    float* out = (float*)d_out;
    float* ws  = (float*)d_ws;

    feats_kernel<<<1024, 256, 0, stream>>>(emb, crf_W, crf_b, ws);
    crf_kernel<<<80, 256, 0, stream>>>(ans, isqa, emb, fc2_W, fc2_b, trans, ws, out);
}